// Round 8
// baseline (396.094 us; speedup 1.0000x reference)
//
#include <hip/hip_runtime.h>
#include <hip/hip_bf16.h>
#include <cmath>

// Problem constants
#define NN 768
#define CS 384
#define CZ 128
#define CH 16
#define HH 12
#define PQ 4
#define PV 8
#define CATC 2112           // H*(CZ+CH+PV*4)

typedef __attribute__((ext_vector_type(8))) __bf16 bf16x8;
typedef __attribute__((ext_vector_type(8))) unsigned short us8;
typedef __attribute__((ext_vector_type(4))) float f32x4;

__device__ __forceinline__ unsigned short f2bf(float f) {
  unsigned int u = __builtin_bit_cast(unsigned int, f);
  u += 0x7FFFu + ((u >> 16) & 1u);   // RNE
  return (unsigned short)(u >> 16);
}
__device__ __forceinline__ float bf2f(unsigned short u) {
  return __builtin_bit_cast(float, ((unsigned int)u) << 16);
}
// native cast -> compiler emits v_cvt_pk_bf16_f32 for pairs
__device__ __forceinline__ unsigned short nf2bf(float f) {
  __bf16 b = (__bf16)f;
  return __builtin_bit_cast(unsigned short, b);
}

// ---------------------------------------------------------------------------
// K1: projections q,k,v,q_pts,kv_pts (with frame application)
// grid 768 blocks x 256 threads
__global__ void k_proj(const float* __restrict__ s, const float* __restrict__ rot,
                       const float* __restrict__ trans,
                       const float* __restrict__ Wq, const float* __restrict__ bq,
                       const float* __restrict__ Wkv, const float* __restrict__ bkv,
                       const float* __restrict__ Wqp, const float* __restrict__ bqp,
                       const float* __restrict__ Wkvp, const float* __restrict__ bkvp,
                       float* __restrict__ q, float* __restrict__ kk, float* __restrict__ vv,
                       float* __restrict__ qpts, float* __restrict__ kvpts) {
  __shared__ float srow[CS];
  __shared__ float rawq[144];
  __shared__ float rawkv[432];
  __shared__ float R[9];
  __shared__ float T[3];
  int n = blockIdx.x, t = threadIdx.x;
  for (int u = t; u < CS; u += 256) srow[u] = s[(size_t)n*CS + u];
  if (t < 9) R[t] = rot[(size_t)n*9 + t];
  if (t < 3) T[t] = trans[(size_t)n*3 + t];
  __syncthreads();

  for (int col = t; col < 192; col += 256) {
    float acc = bq[col];
    for (int c = 0; c < CS; c++) acc += srow[c] * Wq[(size_t)c*192 + col];
    q[(size_t)n*192 + col] = acc;
  }
  for (int col = t; col < 384; col += 256) {
    float acc = bkv[col];
    for (int c = 0; c < CS; c++) acc += srow[c] * Wkv[(size_t)c*384 + col];
    int h = col >> 5, u2 = col & 31;
    if (u2 < 16) kk[(size_t)n*192 + h*16 + u2] = acc;
    else         vv[(size_t)n*192 + h*16 + (u2-16)] = acc;
  }
  for (int col = t; col < 144; col += 256) {
    float acc = bqp[col];
    for (int c = 0; c < CS; c++) acc += srow[c] * Wqp[(size_t)c*144 + col];
    rawq[col] = acc;
  }
  for (int col = t; col < 432; col += 256) {
    float acc = bkvp[col];
    for (int c = 0; c < CS; c++) acc += srow[c] * Wkvp[(size_t)c*432 + col];
    rawkv[col] = acc;
  }
  __syncthreads();

  for (int u = t; u < 48*3; u += 256) {
    int m = u / 3, x = u % 3;
    float p0 = rawq[0*48 + m], p1 = rawq[1*48 + m], p2 = rawq[2*48 + m];
    qpts[((size_t)n*48 + m)*3 + x] = R[x*3+0]*p0 + R[x*3+1]*p1 + R[x*3+2]*p2 + T[x];
  }
  for (int u = t; u < 144*3; u += 256) {
    int m = u / 3, x = u % 3;
    float p0 = rawkv[0*144 + m], p1 = rawkv[1*144 + m], p2 = rawkv[2*144 + m];
    kvpts[((size_t)n*144 + m)*3 + x] = R[x*3+0]*p0 + R[x*3+1]*p1 + R[x*3+2]*p2 + T[x];
  }
}

// ---------------------------------------------------------------------------
// K_prep: augmented B matrix for logits (see R4 notes). grid 48 x 256
__global__ void k_prep(const float* __restrict__ kk, const float* __restrict__ kvpts,
                       unsigned short* __restrict__ Bq) {
  int jt16 = blockIdx.x, t = threadIdx.x;
  for (int u = t; u < 768; u += 256) {
    int hp = u >> 6, kg = (u >> 4) & 3, l15 = u & 15;
    int j = jt16*16 + l15;
    unsigned short vals[8];
    #pragma unroll
    for (int e = 0; e < 8; e++) {
      int cc = kg*8 + e;
      float v;
      if (cc < 16) {
        v = kk[(size_t)j*192 + hp*16 + cc];
      } else if (cc < 28) {
        v = kvpts[(size_t)j*432 + hp*36 + (cc-16)];
      } else if (cc == 28) {
        float s2 = 0.f;
        #pragma unroll
        for (int m = 0; m < 12; m++) {
          float d = kvpts[(size_t)j*432 + hp*36 + m];
          s2 += d*d;
        }
        v = s2;
      } else if (cc == 29) {
        v = 1.0f;
      } else {
        v = 0.f;
      }
      vals[e] = f2bf(v);
    }
    *(us8*)(Bq + ((size_t)(jt16*12 + hp)*64 + kg*16 + l15)*8) = *(const us8*)vals;
  }
}

// ---------------------------------------------------------------------------
// K_prep_v: swizzled bf16 B-matrix for k_ov's per-head GEMM. grid 432 x 256
__global__ void k_prep_v(const float* __restrict__ vv, const float* __restrict__ kvpts,
                         unsigned short* __restrict__ Vq) {
  int g = blockIdx.x*256 + threadIdx.x;   // < 110592
  int l15 = g & 15;
  int kg  = (g >> 4) & 3;
  int r2  = g >> 6;          // ((h*3+nt)*24 + ks)
  int ks  = r2 % 24;
  int hn  = r2 / 24;
  int nt  = hn % 3;
  int h   = hn / 3;
  int col = nt*16 + l15;
  unsigned short vals[8];
  #pragma unroll
  for (int e = 0; e < 8; e++) {
    int j = ks*32 + kg*8 + e;
    float v = 0.f;
    if (col < 16)      v = vv[(size_t)j*192 + h*16 + col];
    else if (col < 40) v = kvpts[(size_t)j*432 + h*36 + 12 + (col-16)];
    vals[e] = f2bf(v);
  }
  *(us8*)(Vq + (size_t)g*8) = *(const us8*)vals;
}

// ---------------------------------------------------------------------------
// K_FUSED: logits (MFMA, z pass 1) -> exact softmax in registers ->
// o_pair (MFMA, z pass 2 via LDS-staged transposed tiles) + bf16 p dump.
// grid 768 (one block per i) x 256.
#define PLD 776   // p_lds row stride in ushorts; rows 4 banks apart
#define ZLD 72    // zt row stride in ushorts (144B)
__global__ void __launch_bounds__(256) k_fused(
    const float* __restrict__ q, const float* __restrict__ qpts,
    const float* __restrict__ z, const float* __restrict__ Wb,
    const float* __restrict__ bb, const float* __restrict__ head_w,
    const unsigned short* __restrict__ Bq,
    unsigned short* __restrict__ p_bf, float* __restrict__ cat) {
  __shared__ float qi[192];
  __shared__ float qpi[144];
  __shared__ unsigned short p_lds[12*PLD];
  __shared__ unsigned short zt[128*ZLD];
  __shared__ float redm[4][16];
  __shared__ float reds[4][16];
  int i = blockIdx.x, t = threadIdx.x;
  int w = t >> 6, l = t & 63, kg = l >> 4, l15 = l & 15;
  for (int u = t; u < 192; u += 256) qi[u] = q[(size_t)i*192 + u];
  for (int u = t; u < 144; u += 256) qpi[u] = qpts[(size_t)i*144 + u];

  const float sc1 = 0.14433756729740643f;   // sqrt(1/48)
  const float sc3 = 0.5773502691896258f;    // sqrt(1/3)
  us8 af[4];
  #pragma unroll
  for (int ks = 0; ks < 4; ks++) {
    #pragma unroll
    for (int kc = 0; kc < 8; kc++) {
      af[ks][kc] = (l15 < 12) ? nf2bf(sc3 * Wb[(size_t)(ks*32 + kg*8 + kc)*12 + l15])
                              : (unsigned short)0;
    }
  }
  __syncthreads();

  // aug A-frag: [sc1*q(16) | hw*qp(12) | -0.5hw | sc3*bb-0.5hw*|qp|^2 | 0 0]
  float hw = (l15 < 12) ? log1pf(expf(head_w[l15])) * 0.13608276348795434f : 0.f;
  us8 aug;
  #pragma unroll
  for (int e = 0; e < 8; e++) {
    int idx = kg*8 + e;
    float v = 0.f;
    if (l15 < 12) {
      if (idx < 16) v = sc1 * qi[l15*16 + idx];
      else if (idx < 28) v = hw * qpi[l15*12 + (idx-16)];
      else if (idx == 28) v = -0.5f * hw;
      else if (idx == 29) {
        float s2 = 0.f;
        #pragma unroll
        for (int m = 0; m < 12; m++) { float d = qpi[l15*12 + m]; s2 += d*d; }
        v = sc3 * bb[l15] - 0.5f * hw * s2;
      }
    }
    aug[e] = nf2bf(v);
  }
  us8 zero8 = {0,0,0,0,0,0,0,0};
  // hoisted one-hot aug A-frags (each lane nonzero in exactly one hp)
  bf16x8 afa[12];
  #pragma unroll
  for (int hp = 0; hp < 12; hp++)
    afa[hp] = __builtin_bit_cast(bf16x8, (l15 == hp) ? aug : zero8);
  const us8* Bq8 = (const us8*)Bq;

  // ---- phase 1: logits, all 12 j-tiles, kept in registers
  f32x4 lg[12];
  #pragma unroll
  for (int jt = 0; jt < 12; jt++) {
    int jcol = jt*64 + w*16 + l15;
    const float* zr = z + ((size_t)i*NN + jcol)*CZ;
    f32x4 accz = {0.f,0.f,0.f,0.f};
    f32x4 aa0 = {0.f,0.f,0.f,0.f}, aa1 = {0.f,0.f,0.f,0.f}, aa2 = {0.f,0.f,0.f,0.f};
    #pragma unroll
    for (int ks = 0; ks < 4; ks++) {
      float4 z0 = *(const float4*)(zr + ks*32 + kg*8);
      float4 z1 = *(const float4*)(zr + ks*32 + kg*8 + 4);
      bf16x8 bv;
      bv[0] = (__bf16)z0.x; bv[1] = (__bf16)z0.y; bv[2] = (__bf16)z0.z; bv[3] = (__bf16)z0.w;
      bv[4] = (__bf16)z1.x; bv[5] = (__bf16)z1.y; bv[6] = (__bf16)z1.z; bv[7] = (__bf16)z1.w;
      accz = __builtin_amdgcn_mfma_f32_16x16x32_bf16(
          __builtin_bit_cast(bf16x8, af[ks]), bv, accz, 0, 0, 0);
    }
    int jtile = jt*4 + w;
    #pragma unroll
    for (int hp = 0; hp < 12; hp++) {
      us8 bqv = Bq8[(size_t)(jtile*12 + hp)*64 + kg*16 + l15];
      f32x4* dst = (hp < 4) ? &aa0 : (hp < 8) ? &aa1 : &aa2;
      *dst = __builtin_amdgcn_mfma_f32_16x16x32_bf16(
          afa[hp], __builtin_bit_cast(bf16x8, bqv), *dst, 0, 0, 0);
    }
    lg[jt] = (accz + aa0) + (aa1 + aa2);
  }

  // ---- phase 2: exact softmax over j for each h = kg*4+r
  float inv[4];
  {
    float mr[4];
    #pragma unroll
    for (int r = 0; r < 4; r++) {
      float m = lg[0][r];
      #pragma unroll
      for (int jt = 1; jt < 12; jt++) m = fmaxf(m, lg[jt][r]);
      #pragma unroll
      for (int off = 1; off < 16; off <<= 1) m = fmaxf(m, __shfl_xor(m, off));
      mr[r] = m;
    }
    if (l15 == 0) {
      #pragma unroll
      for (int r = 0; r < 4; r++) redm[w][kg*4+r] = mr[r];
    }
    __syncthreads();
    float sr[4];
    #pragma unroll
    for (int r = 0; r < 4; r++) {
      int h = kg*4 + r;
      float m = fmaxf(fmaxf(redm[0][h], redm[1][h]), fmaxf(redm[2][h], redm[3][h]));
      float s = 0.f;
      #pragma unroll
      for (int jt = 0; jt < 12; jt++) {
        float e = expf(lg[jt][r] - m);
        lg[jt][r] = e;
        s += e;
      }
      #pragma unroll
      for (int off = 1; off < 16; off <<= 1) s += __shfl_xor(s, off);
      sr[r] = s;
    }
    if (l15 == 0) {
      #pragma unroll
      for (int r = 0; r < 4; r++) reds[w][kg*4+r] = sr[r];
    }
    __syncthreads();
    #pragma unroll
    for (int r = 0; r < 4; r++) {
      int h = kg*4 + r;
      inv[r] = 1.0f / (reds[0][h] + reds[1][h] + reds[2][h] + reds[3][h]);
    }
  }
  // write bf16 probs to LDS (rows = h, padded stride)
  if (kg < 3) {
    #pragma unroll
    for (int jt = 0; jt < 12; jt++) {
      int jcol = jt*64 + w*16 + l15;
      #pragma unroll
      for (int r = 0; r < 4; r++)
        p_lds[(kg*4+r)*PLD + jcol] = nf2bf(lg[jt][r] * inv[r]);
    }
  }
  __syncthreads();

  // coalesced dump of p to global for k_ov
  {
    const us8* pl8 = (const us8*)p_lds;
    us8* pg8 = (us8*)(p_bf + (size_t)i*12*768);
    for (int idx = t; idx < 1152; idx += 256) {
      int h = idx / 96, c8 = idx % 96;
      pg8[h*96 + c8] = pl8[h*97 + c8];
    }
  }

  // ---- phase 3: o_pair = p @ z (z pass 2, L3-warm) via LDS-staged z^T tiles
  {
    int cb = w * 32;
    f32x4 acc0 = {0.f,0.f,0.f,0.f}, acc1 = {0.f,0.f,0.f,0.f};
    int sA = (l15 & 7) << 3;          // read-side XOR (c&7, cb mult of 32)
    for (int jt = 0; jt < 12; jt++) {
      __syncthreads();   // prior tile consumed (first iter: after p dump, harmless)
      // stage z[jt*64..+64][0..128] -> zt[c][j ^ ((c&7)<<3)] bf16
      const float* zb = z + ((size_t)i*NN + jt*64)*CZ;
      #pragma unroll
      for (int k = 0; k < 8; k++) {
        int jloc = w*16 + l15;
        int c4 = k*4 + kg;
        float4 v = *(const float4*)(zb + (size_t)jloc*CZ + c4*4);
        #pragma unroll
        for (int e = 0; e < 4; e++) {
          int c = c4*4 + e;
          float vv_ = (e==0) ? v.x : (e==1) ? v.y : (e==2) ? v.z : v.w;
          zt[c*ZLD + (jloc ^ ((c&7)<<3))] = nf2bf(vv_);
        }
      }
      __syncthreads();
      // 2 K-steps of 32 j
      #pragma unroll
      for (int ks2 = 0; ks2 < 2; ks2++) {
        int j0 = ks2*32 + kg*8;
        us8 av = zero8;
        if (l15 < 12) av = *(const us8*)(p_lds + (size_t)l15*PLD + jt*64 + j0);
        us8 b0 = *(const us8*)(zt + (size_t)(cb + l15)*ZLD + (j0 ^ sA));
        us8 b1 = *(const us8*)(zt + (size_t)(cb + 16 + l15)*ZLD + (j0 ^ sA));
        acc0 = __builtin_amdgcn_mfma_f32_16x16x32_bf16(
            __builtin_bit_cast(bf16x8, av), __builtin_bit_cast(bf16x8, b0), acc0, 0, 0, 0);
        acc1 = __builtin_amdgcn_mfma_f32_16x16x32_bf16(
            __builtin_bit_cast(bf16x8, av), __builtin_bit_cast(bf16x8, b1), acc1, 0, 0, 0);
      }
    }
    #pragma unroll
    for (int r = 0; r < 4; r++) {
      int h = kg*4 + r;
      if (h < 12) {
        float* cc = cat + (size_t)i*CATC + 576 + (size_t)h*128;
        cc[cb + l15]      = acc0[r];
        cc[cb + 16 + l15] = acc1[r];
      }
    }
  }
}

// ---------------------------------------------------------------------------
// K4 (MFMA): per-head GEMM P_h[768x768] @ V_h[768x40] -> o and o_pt(+norm).
// grid (48 i-tiles, 12 h) x 256.
__global__ void k_ov(const unsigned short* __restrict__ p_bf,
                     const unsigned short* __restrict__ Vq,
                     const float* __restrict__ rot, const float* __restrict__ trans,
                     float* __restrict__ cat) {
  __shared__ float opt[16][28];
  __shared__ float Rl[16][9];
  __shared__ float Tl[16][3];
  int it = blockIdx.x, h = blockIdx.y, t = threadIdx.x;
  int i0 = it*16;
  int w = t >> 6, l = t & 63, kg = l >> 4, l15 = l & 15;
  if (t < 144) Rl[t/9][t%9] = rot[(size_t)(i0 + t/9)*9 + (t%9)];
  if (t >= 192 && t < 240) {
    int u = t - 192;
    Tl[u/3][u%3] = trans[(size_t)(i0 + u/3)*3 + (u%3)];
  }
  f32x4 acc = {0.f,0.f,0.f,0.f};
  if (w < 3) {
    const unsigned short* prow = p_bf + ((size_t)(i0 + l15)*12 + h)*768 + kg*8;
    const us8* vq = (const us8*)Vq + (size_t)(h*3 + w)*24*64 + kg*16 + l15;
    for (int ks = 0; ks < 24; ks++) {
      us8 av = *(const us8*)(prow + ks*32);
      us8 bv = vq[(size_t)ks*64];
      acc = __builtin_amdgcn_mfma_f32_16x16x32_bf16(
          __builtin_bit_cast(bf16x8, av), __builtin_bit_cast(bf16x8, bv), acc, 0, 0, 0);
    }
  }
  if (w == 0) {
    #pragma unroll
    for (int r = 0; r < 4; r++)
      cat[(size_t)(i0 + kg*4 + r)*CATC + h*16 + l15] = acc[r];
  } else if (w == 1) {
    #pragma unroll
    for (int r = 0; r < 4; r++) opt[kg*4 + r][l15] = acc[r];
  } else if (w == 2) {
    if (l15 < 8) {
      #pragma unroll
      for (int r = 0; r < 4; r++) opt[kg*4 + r][16 + l15] = acc[r];
    }
  }
  __syncthreads();
  if (t < 128) {
    int ip = t >> 3, p = t & 7;
    float x0 = opt[ip][p*3+0] - Tl[ip][0];
    float x1 = opt[ip][p*3+1] - Tl[ip][1];
    float x2 = opt[ip][p*3+2] - Tl[ip][2];
    const float* R = Rl[ip];
    float ox = R[0]*x0 + R[3]*x1 + R[6]*x2;
    float oy = R[1]*x0 + R[4]*x1 + R[7]*x2;
    float oz = R[2]*x0 + R[5]*x1 + R[8]*x2;
    float nrm = sqrtf(ox*ox + oy*oy + oz*oz + 1e-8f);
    float* c = cat + (size_t)(i0 + ip)*CATC;
    int m = h*8 + p;
    c[192 + m] = ox; c[288 + m] = oy; c[384 + m] = oz; c[480 + m] = nrm;
  }
}

// ---------------------------------------------------------------------------
// K6: out = cat @ Wout + bout. ROWS=3/block -> grid 256, x8-unrolled loads.
#define OROWS 3
__global__ void k_out(const float* __restrict__ cat, const float* __restrict__ Wout,
                      const float* __restrict__ bout, float* __restrict__ out) {
  __shared__ float cl[OROWS*CATC];
  int i0 = blockIdx.x*OROWS, t = threadIdx.x;
  for (int idx = t; idx < OROWS*CATC; idx += 384) cl[idx] = cat[(size_t)i0*CATC + idx];
  __syncthreads();
  float acc[OROWS];
  #pragma unroll
  for (int g = 0; g < OROWS; g++) acc[g] = 0.f;
  for (int r = 0; r < CATC; r += 8) {
    float wv[8];
    #pragma unroll
    for (int u = 0; u < 8; u++) wv[u] = Wout[(size_t)(r+u)*384 + t];
    #pragma unroll
    for (int u = 0; u < 8; u++) {
      #pragma unroll
      for (int g = 0; g < OROWS; g++) acc[g] += cl[g*CATC + r + u] * wv[u];
    }
  }
  float bo = bout[t];
  #pragma unroll
  for (int g = 0; g < OROWS; g++) out[(size_t)(i0+g)*384 + t] = acc[g] + bo;
}

// ---------------------------------------------------------------------------
extern "C" void kernel_launch(void* const* d_in, const int* in_sizes, int n_in,
                              void* d_out, int out_size, void* d_ws, size_t ws_size,
                              hipStream_t stream) {
  const float* s      = (const float*)d_in[0];
  const float* z      = (const float*)d_in[1];
  const float* rot    = (const float*)d_in[2];
  const float* trans  = (const float*)d_in[3];
  const float* Wq     = (const float*)d_in[4];
  const float* bq     = (const float*)d_in[5];
  const float* Wkv    = (const float*)d_in[6];
  const float* bkv    = (const float*)d_in[7];
  const float* Wqp    = (const float*)d_in[8];
  const float* bqp    = (const float*)d_in[9];
  const float* Wkvp   = (const float*)d_in[10];
  const float* bkvp   = (const float*)d_in[11];
  const float* Wb     = (const float*)d_in[12];
  const float* bb     = (const float*)d_in[13];
  const float* head_w = (const float*)d_in[14];
  const float* Wout   = (const float*)d_in[15];
  const float* bout   = (const float*)d_in[16];
  float* out = (float*)d_out;

  float* ws    = (float*)d_ws;
  float* q     = ws;                    // 147456
  float* kk    = q     + 147456;        // 147456
  float* vv    = kk    + 147456;        // 147456
  float* qpts  = vv    + 147456;        // 110592
  float* kvpts = qpts  + 110592;        // 331776
  unsigned short* p_bf = (unsigned short*)(kvpts + 331776); // 7077888 bf16 probs
  float* cat   = (float*)(p_bf + 7077888);                  // 1622016
  unsigned short* Bq = (unsigned short*)(cat + 1622016);    // 294912 bf16
  unsigned short* Vq = Bq + 294912;                         // 884736 bf16

  k_proj<<<768, 256, 0, stream>>>(s, rot, trans, Wq, bq, Wkv, bkv, Wqp, bqp,
                                  Wkvp, bkvp, q, kk, vv, qpts, kvpts);
  k_prep<<<48, 256, 0, stream>>>(kk, kvpts, Bq);
  k_prep_v<<<432, 256, 0, stream>>>(vv, kvpts, Vq);
  k_fused<<<768, 256, 0, stream>>>(q, qpts, z, Wb, bb, head_w, Bq, p_bf, cat);
  k_ov<<<dim3(48, 12), 256, 0, stream>>>(p_bf, Vq, rot, trans, cat);
  k_out<<<256, 384, 0, stream>>>(cat, Wout, bout, out);
}

// Round 9
// 388.504 us; speedup vs baseline: 1.0195x; 1.0195x over previous
//
#include <hip/hip_runtime.h>
#include <hip/hip_bf16.h>
#include <cmath>

// Problem constants
#define NN 768
#define CS 384
#define CZ 128
#define CH 16
#define HH 12
#define PQ 4
#define PV 8
#define CATC 2112           // H*(CZ+CH+PV*4)

typedef __attribute__((ext_vector_type(8))) __bf16 bf16x8;
typedef __attribute__((ext_vector_type(8))) unsigned short us8;
typedef __attribute__((ext_vector_type(4))) float f32x4;

__device__ __forceinline__ unsigned short f2bf(float f) {
  unsigned int u = __builtin_bit_cast(unsigned int, f);
  u += 0x7FFFu + ((u >> 16) & 1u);   // RNE
  return (unsigned short)(u >> 16);
}
__device__ __forceinline__ float bf2f(unsigned short u) {
  return __builtin_bit_cast(float, ((unsigned int)u) << 16);
}
// native cast -> compiler emits v_cvt_pk_bf16_f32 for pairs
__device__ __forceinline__ unsigned short nf2bf(float f) {
  __bf16 b = (__bf16)f;
  return __builtin_bit_cast(unsigned short, b);
}

// ---------------------------------------------------------------------------
// K1: projections q,k,v,q_pts,kv_pts (with frame application)
// grid 768 blocks x 256 threads
__global__ void k_proj(const float* __restrict__ s, const float* __restrict__ rot,
                       const float* __restrict__ trans,
                       const float* __restrict__ Wq, const float* __restrict__ bq,
                       const float* __restrict__ Wkv, const float* __restrict__ bkv,
                       const float* __restrict__ Wqp, const float* __restrict__ bqp,
                       const float* __restrict__ Wkvp, const float* __restrict__ bkvp,
                       float* __restrict__ q, float* __restrict__ kk, float* __restrict__ vv,
                       float* __restrict__ qpts, float* __restrict__ kvpts) {
  __shared__ float srow[CS];
  __shared__ float rawq[144];
  __shared__ float rawkv[432];
  __shared__ float R[9];
  __shared__ float T[3];
  int n = blockIdx.x, t = threadIdx.x;
  for (int u = t; u < CS; u += 256) srow[u] = s[(size_t)n*CS + u];
  if (t < 9) R[t] = rot[(size_t)n*9 + t];
  if (t < 3) T[t] = trans[(size_t)n*3 + t];
  __syncthreads();

  for (int col = t; col < 192; col += 256) {
    float acc = bq[col];
    for (int c = 0; c < CS; c++) acc += srow[c] * Wq[(size_t)c*192 + col];
    q[(size_t)n*192 + col] = acc;
  }
  for (int col = t; col < 384; col += 256) {
    float acc = bkv[col];
    for (int c = 0; c < CS; c++) acc += srow[c] * Wkv[(size_t)c*384 + col];
    int h = col >> 5, u2 = col & 31;
    if (u2 < 16) kk[(size_t)n*192 + h*16 + u2] = acc;
    else         vv[(size_t)n*192 + h*16 + (u2-16)] = acc;
  }
  for (int col = t; col < 144; col += 256) {
    float acc = bqp[col];
    for (int c = 0; c < CS; c++) acc += srow[c] * Wqp[(size_t)c*144 + col];
    rawq[col] = acc;
  }
  for (int col = t; col < 432; col += 256) {
    float acc = bkvp[col];
    for (int c = 0; c < CS; c++) acc += srow[c] * Wkvp[(size_t)c*432 + col];
    rawkv[col] = acc;
  }
  __syncthreads();

  for (int u = t; u < 48*3; u += 256) {
    int m = u / 3, x = u % 3;
    float p0 = rawq[0*48 + m], p1 = rawq[1*48 + m], p2 = rawq[2*48 + m];
    qpts[((size_t)n*48 + m)*3 + x] = R[x*3+0]*p0 + R[x*3+1]*p1 + R[x*3+2]*p2 + T[x];
  }
  for (int u = t; u < 144*3; u += 256) {
    int m = u / 3, x = u % 3;
    float p0 = rawkv[0*144 + m], p1 = rawkv[1*144 + m], p2 = rawkv[2*144 + m];
    kvpts[((size_t)n*144 + m)*3 + x] = R[x*3+0]*p0 + R[x*3+1]*p1 + R[x*3+2]*p2 + T[x];
  }
}

// ---------------------------------------------------------------------------
// K_prep: augmented B matrix for logits (see R4 notes). grid 48 x 256
__global__ void k_prep(const float* __restrict__ kk, const float* __restrict__ kvpts,
                       unsigned short* __restrict__ Bq) {
  int jt16 = blockIdx.x, t = threadIdx.x;
  for (int u = t; u < 768; u += 256) {
    int hp = u >> 6, kg = (u >> 4) & 3, l15 = u & 15;
    int j = jt16*16 + l15;
    unsigned short vals[8];
    #pragma unroll
    for (int e = 0; e < 8; e++) {
      int cc = kg*8 + e;
      float v;
      if (cc < 16) {
        v = kk[(size_t)j*192 + hp*16 + cc];
      } else if (cc < 28) {
        v = kvpts[(size_t)j*432 + hp*36 + (cc-16)];
      } else if (cc == 28) {
        float s2 = 0.f;
        #pragma unroll
        for (int m = 0; m < 12; m++) {
          float d = kvpts[(size_t)j*432 + hp*36 + m];
          s2 += d*d;
        }
        v = s2;
      } else if (cc == 29) {
        v = 1.0f;
      } else {
        v = 0.f;
      }
      vals[e] = f2bf(v);
    }
    *(us8*)(Bq + ((size_t)(jt16*12 + hp)*64 + kg*16 + l15)*8) = *(const us8*)vals;
  }
}

// ---------------------------------------------------------------------------
// K_prep_v: swizzled bf16 B-matrix for k_ov's per-head GEMM. grid 432 x 256
__global__ void k_prep_v(const float* __restrict__ vv, const float* __restrict__ kvpts,
                         unsigned short* __restrict__ Vq) {
  int g = blockIdx.x*256 + threadIdx.x;   // < 110592
  int l15 = g & 15;
  int kg  = (g >> 4) & 3;
  int r2  = g >> 6;          // ((h*3+nt)*24 + ks)
  int ks  = r2 % 24;
  int hn  = r2 / 24;
  int nt  = hn % 3;
  int h   = hn / 3;
  int col = nt*16 + l15;
  unsigned short vals[8];
  #pragma unroll
  for (int e = 0; e < 8; e++) {
    int j = ks*32 + kg*8 + e;
    float v = 0.f;
    if (col < 16)      v = vv[(size_t)j*192 + h*16 + col];
    else if (col < 40) v = kvpts[(size_t)j*432 + h*36 + 12 + (col-16)];
    vals[e] = f2bf(v);
  }
  *(us8*)(Vq + (size_t)g*8) = *(const us8*)vals;
}

// ---------------------------------------------------------------------------
// K_FUSED v3: 512 threads / 8 waves (grid-limited occupancy 12->24 waves/CU).
// Phase 1: logits via MFMA, 6x 128-j supertiles (wave owns 16-j column).
// Phase 2: exact softmax, cross-8-wave LDS reduce.
// Phase 3: o_pair, K-split across wave halves, zt swizzle fixed for banks.
// grid 768 (one block per i) x 512.
#define PLD 776   // p_lds row stride in ushorts; rows 4 banks apart
#define ZLD 72    // zt row stride in ushorts (144B)
__global__ void __launch_bounds__(512) k_fused(
    const float* __restrict__ q, const float* __restrict__ qpts,
    const float* __restrict__ z, const float* __restrict__ Wb,
    const float* __restrict__ bb, const float* __restrict__ head_w,
    const unsigned short* __restrict__ Bq,
    unsigned short* __restrict__ p_bf, float* __restrict__ cat) {
  __shared__ float qi[192];
  __shared__ float qpi[144];
  __shared__ unsigned short p_lds[12*PLD];    // 18.2 KB
  __shared__ unsigned short zt[128*ZLD];      // 18.0 KB
  __shared__ float redm[8][16];
  __shared__ float reds[8][16];
  __shared__ float pacc[4][16][32];           // 8 KB
  int i = blockIdx.x, t = threadIdx.x;
  int w = t >> 6, l = t & 63, kg = l >> 4, l15 = l & 15;
  for (int u = t; u < 192; u += 512) qi[u] = q[(size_t)i*192 + u];
  for (int u = t; u < 144; u += 512) qpi[u] = qpts[(size_t)i*144 + u];

  const float sc1 = 0.14433756729740643f;   // sqrt(1/48)
  const float sc3 = 0.5773502691896258f;    // sqrt(1/3)
  us8 af[4];
  #pragma unroll
  for (int ks = 0; ks < 4; ks++) {
    #pragma unroll
    for (int kc = 0; kc < 8; kc++) {
      af[ks][kc] = (l15 < 12) ? nf2bf(sc3 * Wb[(size_t)(ks*32 + kg*8 + kc)*12 + l15])
                              : (unsigned short)0;
    }
  }
  __syncthreads();

  // aug A-frag: [sc1*q(16) | hw*qp(12) | -0.5hw | sc3*bb-0.5hw*|qp|^2 | 0 0]
  float hw = (l15 < 12) ? log1pf(expf(head_w[l15])) * 0.13608276348795434f : 0.f;
  us8 aug;
  #pragma unroll
  for (int e = 0; e < 8; e++) {
    int idx = kg*8 + e;
    float v = 0.f;
    if (l15 < 12) {
      if (idx < 16) v = sc1 * qi[l15*16 + idx];
      else if (idx < 28) v = hw * qpi[l15*12 + (idx-16)];
      else if (idx == 28) v = -0.5f * hw;
      else if (idx == 29) {
        float s2 = 0.f;
        #pragma unroll
        for (int m = 0; m < 12; m++) { float d = qpi[l15*12 + m]; s2 += d*d; }
        v = sc3 * bb[l15] - 0.5f * hw * s2;
      }
    }
    aug[e] = nf2bf(v);
  }
  us8 zero8 = {0,0,0,0,0,0,0,0};
  const us8* Bq8 = (const us8*)Bq;

  // ---- phase 1: logits; wave w owns j-column w*16 of each 128-j supertile
  f32x4 lg[6];
  #pragma unroll
  for (int jt2 = 0; jt2 < 6; jt2++) {
    int jcol = jt2*128 + w*16 + l15;
    const float* zr = z + ((size_t)i*NN + jcol)*CZ;
    f32x4 accz = {0.f,0.f,0.f,0.f};
    f32x4 aa0 = {0.f,0.f,0.f,0.f}, aa1 = {0.f,0.f,0.f,0.f}, aa2 = {0.f,0.f,0.f,0.f};
    #pragma unroll
    for (int ks = 0; ks < 4; ks++) {
      float4 z0 = *(const float4*)(zr + ks*32 + kg*8);
      float4 z1 = *(const float4*)(zr + ks*32 + kg*8 + 4);
      bf16x8 bv;
      bv[0] = (__bf16)z0.x; bv[1] = (__bf16)z0.y; bv[2] = (__bf16)z0.z; bv[3] = (__bf16)z0.w;
      bv[4] = (__bf16)z1.x; bv[5] = (__bf16)z1.y; bv[6] = (__bf16)z1.z; bv[7] = (__bf16)z1.w;
      accz = __builtin_amdgcn_mfma_f32_16x16x32_bf16(
          __builtin_bit_cast(bf16x8, af[ks]), bv, accz, 0, 0, 0);
    }
    int jtile = jt2*8 + w;
    #pragma unroll
    for (int hp = 0; hp < 12; hp++) {
      us8 bqv = Bq8[(size_t)(jtile*12 + hp)*64 + kg*16 + l15];
      us8 sel = (l15 == hp) ? aug : zero8;
      f32x4* dst = (hp < 4) ? &aa0 : (hp < 8) ? &aa1 : &aa2;
      *dst = __builtin_amdgcn_mfma_f32_16x16x32_bf16(
          __builtin_bit_cast(bf16x8, sel), __builtin_bit_cast(bf16x8, bqv), *dst, 0, 0, 0);
    }
    lg[jt2] = (accz + aa0) + (aa1 + aa2);
  }

  // ---- phase 2: exact softmax over j for each h = kg*4+r
  float inv[4];
  {
    float mr[4];
    #pragma unroll
    for (int r = 0; r < 4; r++) {
      float m = lg[0][r];
      #pragma unroll
      for (int jt2 = 1; jt2 < 6; jt2++) m = fmaxf(m, lg[jt2][r]);
      #pragma unroll
      for (int off = 1; off < 16; off <<= 1) m = fmaxf(m, __shfl_xor(m, off));
      mr[r] = m;
    }
    if (l15 == 0) {
      #pragma unroll
      for (int r = 0; r < 4; r++) redm[w][kg*4+r] = mr[r];
    }
    __syncthreads();
    float sr[4];
    #pragma unroll
    for (int r = 0; r < 4; r++) {
      int h = kg*4 + r;
      float m = redm[0][h];
      #pragma unroll
      for (int ww = 1; ww < 8; ww++) m = fmaxf(m, redm[ww][h]);
      float s = 0.f;
      #pragma unroll
      for (int jt2 = 0; jt2 < 6; jt2++) {
        float e = expf(lg[jt2][r] - m);
        lg[jt2][r] = e;
        s += e;
      }
      #pragma unroll
      for (int off = 1; off < 16; off <<= 1) s += __shfl_xor(s, off);
      sr[r] = s;
    }
    if (l15 == 0) {
      #pragma unroll
      for (int r = 0; r < 4; r++) reds[w][kg*4+r] = sr[r];
    }
    __syncthreads();
    #pragma unroll
    for (int r = 0; r < 4; r++) {
      int h = kg*4 + r;
      float s = reds[0][h];
      #pragma unroll
      for (int ww = 1; ww < 8; ww++) s += reds[ww][h];
      inv[r] = 1.0f / s;
    }
  }
  // write bf16 probs to LDS (rows = h, padded stride)
  if (kg < 3) {
    #pragma unroll
    for (int jt2 = 0; jt2 < 6; jt2++) {
      int jcol = jt2*128 + w*16 + l15;
      #pragma unroll
      for (int r = 0; r < 4; r++)
        p_lds[(kg*4+r)*PLD + jcol] = nf2bf(lg[jt2][r] * inv[r]);
    }
  }
  __syncthreads();

  // coalesced dump of p to global for k_ov
  {
    const us8* pl8 = (const us8*)p_lds;
    us8* pg8 = (us8*)(p_bf + (size_t)i*12*768);
    for (int idx = t; idx < 1152; idx += 512) {
      int h = idx / 96, c8 = idx % 96;
      pg8[h*96 + c8] = pl8[h*97 + c8];
    }
  }

  // ---- phase 3: o_pair = p @ z (z pass 2, L3-warm) via LDS-staged z^T tiles.
  // Wave halves split K within each 64-j tile; partials combined via pacc.
  {
    int half = w >> 2, cb = (w & 3) * 32;
    int chunk = t & 7, jloc_s = t >> 3;     // staging: c-octet, j-row
    f32x4 acc0 = {0.f,0.f,0.f,0.f}, acc1 = {0.f,0.f,0.f,0.f};
    for (int jt = 0; jt < 12; jt++) {
      __syncthreads();   // prior tile consumed
      const float* zb = z + ((size_t)i*NN + jt*64)*CZ;
      #pragma unroll
      for (int qd = 0; qd < 4; qd++) {
        float4 v = *(const float4*)(zb + (size_t)jloc_s*CZ + chunk*16 + qd*4);
        #pragma unroll
        for (int e = 0; e < 4; e++) {
          int c = chunk*16 + qd*4 + e;
          float vv_ = (e==0) ? v.x : (e==1) ? v.y : (e==2) ? v.z : v.w;
          int sw = (((c & 7) ^ ((c >> 4) & 7)) << 3);
          zt[c*ZLD + (jloc_s ^ sw)] = nf2bf(vv_);
        }
      }
      __syncthreads();
      int j0 = half*32 + kg*8;
      us8 av = zero8;
      if (l15 < 12) av = *(const us8*)(p_lds + (size_t)l15*PLD + jt*64 + j0);
      int c0 = cb + l15, c1 = cb + 16 + l15;
      int sw0 = (((c0 & 7) ^ ((c0 >> 4) & 7)) << 3);
      int sw1 = (((c1 & 7) ^ ((c1 >> 4) & 7)) << 3);
      us8 b0 = *(const us8*)(zt + (size_t)c0*ZLD + (j0 ^ sw0));
      us8 b1 = *(const us8*)(zt + (size_t)c1*ZLD + (j0 ^ sw1));
      acc0 = __builtin_amdgcn_mfma_f32_16x16x32_bf16(
          __builtin_bit_cast(bf16x8, av), __builtin_bit_cast(bf16x8, b0), acc0, 0, 0, 0);
      acc1 = __builtin_amdgcn_mfma_f32_16x16x32_bf16(
          __builtin_bit_cast(bf16x8, av), __builtin_bit_cast(bf16x8, b1), acc1, 0, 0, 0);
    }
    if (half == 1) {
      #pragma unroll
      for (int r = 0; r < 4; r++) {
        pacc[w & 3][kg*4 + r][l15]      = acc0[r];
        pacc[w & 3][kg*4 + r][16 + l15] = acc1[r];
      }
    }
    __syncthreads();
    if (half == 0) {
      #pragma unroll
      for (int r = 0; r < 4; r++) {
        int h = kg*4 + r;
        if (h < 12) {
          float* cc = cat + (size_t)i*CATC + 576 + (size_t)h*128;
          cc[cb + l15]      = acc0[r] + pacc[w][h][l15];
          cc[cb + 16 + l15] = acc1[r] + pacc[w][h][16 + l15];
        }
      }
    }
  }
}

// ---------------------------------------------------------------------------
// K4 (MFMA): per-head GEMM P_h[768x768] @ V_h[768x40] -> o and o_pt(+norm).
// grid (48 i-tiles, 12 h) x 256.
__global__ void k_ov(const unsigned short* __restrict__ p_bf,
                     const unsigned short* __restrict__ Vq,
                     const float* __restrict__ rot, const float* __restrict__ trans,
                     float* __restrict__ cat) {
  __shared__ float opt[16][28];
  __shared__ float Rl[16][9];
  __shared__ float Tl[16][3];
  int it = blockIdx.x, h = blockIdx.y, t = threadIdx.x;
  int i0 = it*16;
  int w = t >> 6, l = t & 63, kg = l >> 4, l15 = l & 15;
  if (t < 144) Rl[t/9][t%9] = rot[(size_t)(i0 + t/9)*9 + (t%9)];
  if (t >= 192 && t < 240) {
    int u = t - 192;
    Tl[u/3][u%3] = trans[(size_t)(i0 + u/3)*3 + (u%3)];
  }
  f32x4 acc = {0.f,0.f,0.f,0.f};
  if (w < 3) {
    const unsigned short* prow = p_bf + ((size_t)(i0 + l15)*12 + h)*768 + kg*8;
    const us8* vq = (const us8*)Vq + (size_t)(h*3 + w)*24*64 + kg*16 + l15;
    for (int ks = 0; ks < 24; ks++) {
      us8 av = *(const us8*)(prow + ks*32);
      us8 bv = vq[(size_t)ks*64];
      acc = __builtin_amdgcn_mfma_f32_16x16x32_bf16(
          __builtin_bit_cast(bf16x8, av), __builtin_bit_cast(bf16x8, bv), acc, 0, 0, 0);
    }
  }
  if (w == 0) {
    #pragma unroll
    for (int r = 0; r < 4; r++)
      cat[(size_t)(i0 + kg*4 + r)*CATC + h*16 + l15] = acc[r];
  } else if (w == 1) {
    #pragma unroll
    for (int r = 0; r < 4; r++) opt[kg*4 + r][l15] = acc[r];
  } else if (w == 2) {
    if (l15 < 8) {
      #pragma unroll
      for (int r = 0; r < 4; r++) opt[kg*4 + r][16 + l15] = acc[r];
    }
  }
  __syncthreads();
  if (t < 128) {
    int ip = t >> 3, p = t & 7;
    float x0 = opt[ip][p*3+0] - Tl[ip][0];
    float x1 = opt[ip][p*3+1] - Tl[ip][1];
    float x2 = opt[ip][p*3+2] - Tl[ip][2];
    const float* R = Rl[ip];
    float ox = R[0]*x0 + R[3]*x1 + R[6]*x2;
    float oy = R[1]*x0 + R[4]*x1 + R[7]*x2;
    float oz = R[2]*x0 + R[5]*x1 + R[8]*x2;
    float nrm = sqrtf(ox*ox + oy*oy + oz*oz + 1e-8f);
    float* c = cat + (size_t)(i0 + ip)*CATC;
    int m = h*8 + p;
    c[192 + m] = ox; c[288 + m] = oy; c[384 + m] = oz; c[480 + m] = nrm;
  }
}

// ---------------------------------------------------------------------------
// K6: out = cat @ Wout + bout. ROWS=3/block -> grid 256, x8-unrolled loads.
#define OROWS 3
__global__ void k_out(const float* __restrict__ cat, const float* __restrict__ Wout,
                      const float* __restrict__ bout, float* __restrict__ out) {
  __shared__ float cl[OROWS*CATC];
  int i0 = blockIdx.x*OROWS, t = threadIdx.x;
  for (int idx = t; idx < OROWS*CATC; idx += 384) cl[idx] = cat[(size_t)i0*CATC + idx];
  __syncthreads();
  float acc[OROWS];
  #pragma unroll
  for (int g = 0; g < OROWS; g++) acc[g] = 0.f;
  for (int r = 0; r < CATC; r += 8) {
    float wv[8];
    #pragma unroll
    for (int u = 0; u < 8; u++) wv[u] = Wout[(size_t)(r+u)*384 + t];
    #pragma unroll
    for (int u = 0; u < 8; u++) {
      #pragma unroll
      for (int g = 0; g < OROWS; g++) acc[g] += cl[g*CATC + r + u] * wv[u];
    }
  }
  float bo = bout[t];
  #pragma unroll
  for (int g = 0; g < OROWS; g++) out[(size_t)(i0+g)*384 + t] = acc[g] + bo;
}

// ---------------------------------------------------------------------------
extern "C" void kernel_launch(void* const* d_in, const int* in_sizes, int n_in,
                              void* d_out, int out_size, void* d_ws, size_t ws_size,
                              hipStream_t stream) {
  const float* s      = (const float*)d_in[0];
  const float* z      = (const float*)d_in[1];
  const float* rot    = (const float*)d_in[2];
  const float* trans  = (const float*)d_in[3];
  const float* Wq     = (const float*)d_in[4];
  const float* bq     = (const float*)d_in[5];
  const float* Wkv    = (const float*)d_in[6];
  const float* bkv    = (const float*)d_in[7];
  const float* Wqp    = (const float*)d_in[8];
  const float* bqp    = (const float*)d_in[9];
  const float* Wkvp   = (const float*)d_in[10];
  const float* bkvp   = (const float*)d_in[11];
  const float* Wb     = (const float*)d_in[12];
  const float* bb     = (const float*)d_in[13];
  const float* head_w = (const float*)d_in[14];
  const float* Wout   = (const float*)d_in[15];
  const float* bout   = (const float*)d_in[16];
  float* out = (float*)d_out;

  float* ws    = (float*)d_ws;
  float* q     = ws;                    // 147456
  float* kk    = q     + 147456;        // 147456
  float* vv    = kk    + 147456;        // 147456
  float* qpts  = vv    + 147456;        // 110592
  float* kvpts = qpts  + 110592;        // 331776
  unsigned short* p_bf = (unsigned short*)(kvpts + 331776); // 7077888 bf16 probs
  float* cat   = (float*)(p_bf + 7077888);                  // 1622016
  unsigned short* Bq = (unsigned short*)(cat + 1622016);    // 294912 bf16
  unsigned short* Vq = Bq + 294912;                         // 884736 bf16

  k_proj<<<768, 256, 0, stream>>>(s, rot, trans, Wq, bq, Wkv, bkv, Wqp, bqp,
                                  Wkvp, bkvp, q, kk, vv, qpts, kvpts);
  k_prep<<<48, 256, 0, stream>>>(kk, kvpts, Bq);
  k_prep_v<<<432, 256, 0, stream>>>(vv, kvpts, Vq);
  k_fused<<<768, 512, 0, stream>>>(q, qpts, z, Wb, bb, head_w, Bq, p_bf, cat);
  k_ov<<<dim3(48, 12), 256, 0, stream>>>(p_bf, Vq, rot, trans, cat);
  k_out<<<256, 384, 0, stream>>>(cat, Wout, bout, out);
}

// Round 10
// 362.354 us; speedup vs baseline: 1.0931x; 1.0722x over previous
//
#include <hip/hip_runtime.h>
#include <hip/hip_bf16.h>
#include <cmath>

// Problem constants
#define NN 768
#define CS 384
#define CZ 128
#define CH 16
#define HH 12
#define PQ 4
#define PV 8
#define CATC 2112           // H*(CZ+CH+PV*4)

typedef __attribute__((ext_vector_type(8))) __bf16 bf16x8;
typedef __attribute__((ext_vector_type(8))) unsigned short us8;
typedef __attribute__((ext_vector_type(4))) float f32x4;

__device__ __forceinline__ unsigned short f2bf(float f) {
  unsigned int u = __builtin_bit_cast(unsigned int, f);
  u += 0x7FFFu + ((u >> 16) & 1u);   // RNE
  return (unsigned short)(u >> 16);
}
__device__ __forceinline__ float bf2f(unsigned short u) {
  return __builtin_bit_cast(float, ((unsigned int)u) << 16);
}
__device__ __forceinline__ unsigned short nf2bf(float f) {
  __bf16 b = (__bf16)f;
  return __builtin_bit_cast(unsigned short, b);
}

// ---------------------------------------------------------------------------
// K1: projections q,k,v,q_pts,kv_pts (with frame application). grid 768 x 256
__global__ void k_proj(const float* __restrict__ s, const float* __restrict__ rot,
                       const float* __restrict__ trans,
                       const float* __restrict__ Wq, const float* __restrict__ bq,
                       const float* __restrict__ Wkv, const float* __restrict__ bkv,
                       const float* __restrict__ Wqp, const float* __restrict__ bqp,
                       const float* __restrict__ Wkvp, const float* __restrict__ bkvp,
                       float* __restrict__ q, float* __restrict__ kk, float* __restrict__ vv,
                       float* __restrict__ qpts, float* __restrict__ kvpts) {
  __shared__ float srow[CS];
  __shared__ float rawq[144];
  __shared__ float rawkv[432];
  __shared__ float R[9];
  __shared__ float T[3];
  int n = blockIdx.x, t = threadIdx.x;
  for (int u = t; u < CS; u += 256) srow[u] = s[(size_t)n*CS + u];
  if (t < 9) R[t] = rot[(size_t)n*9 + t];
  if (t < 3) T[t] = trans[(size_t)n*3 + t];
  __syncthreads();

  for (int col = t; col < 192; col += 256) {
    float acc = bq[col];
    for (int c = 0; c < CS; c++) acc += srow[c] * Wq[(size_t)c*192 + col];
    q[(size_t)n*192 + col] = acc;
  }
  for (int col = t; col < 384; col += 256) {
    float acc = bkv[col];
    for (int c = 0; c < CS; c++) acc += srow[c] * Wkv[(size_t)c*384 + col];
    int h = col >> 5, u2 = col & 31;
    if (u2 < 16) kk[(size_t)n*192 + h*16 + u2] = acc;
    else         vv[(size_t)n*192 + h*16 + (u2-16)] = acc;
  }
  for (int col = t; col < 144; col += 256) {
    float acc = bqp[col];
    for (int c = 0; c < CS; c++) acc += srow[c] * Wqp[(size_t)c*144 + col];
    rawq[col] = acc;
  }
  for (int col = t; col < 432; col += 256) {
    float acc = bkvp[col];
    for (int c = 0; c < CS; c++) acc += srow[c] * Wkvp[(size_t)c*432 + col];
    rawkv[col] = acc;
  }
  __syncthreads();

  for (int u = t; u < 48*3; u += 256) {
    int m = u / 3, x = u % 3;
    float p0 = rawq[0*48 + m], p1 = rawq[1*48 + m], p2 = rawq[2*48 + m];
    qpts[((size_t)n*48 + m)*3 + x] = R[x*3+0]*p0 + R[x*3+1]*p1 + R[x*3+2]*p2 + T[x];
  }
  for (int u = t; u < 144*3; u += 256) {
    int m = u / 3, x = u % 3;
    float p0 = rawkv[0*144 + m], p1 = rawkv[1*144 + m], p2 = rawkv[2*144 + m];
    kvpts[((size_t)n*144 + m)*3 + x] = R[x*3+0]*p0 + R[x*3+1]*p1 + R[x*3+2]*p2 + T[x];
  }
}

// ---------------------------------------------------------------------------
// K_prep: augmented B matrix for logits + afT (sc3*Wb^T frags). grid 48 x 256
__global__ void k_prep(const float* __restrict__ kk, const float* __restrict__ kvpts,
                       const float* __restrict__ Wb,
                       unsigned short* __restrict__ Bq, unsigned short* __restrict__ afT) {
  int jt16 = blockIdx.x, t = threadIdx.x;
  for (int u = t; u < 768; u += 256) {
    int hp = u >> 6, kg = (u >> 4) & 3, l15 = u & 15;
    int j = jt16*16 + l15;
    unsigned short vals[8];
    #pragma unroll
    for (int e = 0; e < 8; e++) {
      int cc = kg*8 + e;
      float v;
      if (cc < 16) {
        v = kk[(size_t)j*192 + hp*16 + cc];
      } else if (cc < 28) {
        v = kvpts[(size_t)j*432 + hp*36 + (cc-16)];
      } else if (cc == 28) {
        float s2 = 0.f;
        #pragma unroll
        for (int m = 0; m < 12; m++) {
          float d = kvpts[(size_t)j*432 + hp*36 + m];
          s2 += d*d;
        }
        v = s2;
      } else if (cc == 29) {
        v = 1.0f;
      } else {
        v = 0.f;
      }
      vals[e] = f2bf(v);
    }
    *(us8*)(Bq + ((size_t)(jt16*12 + hp)*64 + kg*16 + l15)*8) = *(const us8*)vals;
  }
  // afT[kg][l15][ks]: sc3*Wb^T fragment table (i-independent)
  if (blockIdx.x == 0) {
    int kg = t >> 6, l15 = (t >> 2) & 15, ks = t & 3;
    unsigned short vals[8];
    #pragma unroll
    for (int kc = 0; kc < 8; kc++) {
      vals[kc] = (l15 < 12)
        ? f2bf(0.5773502691896258f * Wb[(size_t)(ks*32 + kg*8 + kc)*12 + l15])
        : (unsigned short)0;
    }
    *(us8*)(afT + (size_t)t*8) = *(const us8*)vals;
  }
}

// ---------------------------------------------------------------------------
// K_prep_aug: augT[i][kg][l15] us8 = aug A-frag table. grid 192 x 256
__global__ void k_prep_aug(const float* __restrict__ q, const float* __restrict__ qpts,
                           const float* __restrict__ bb, const float* __restrict__ head_w,
                           unsigned short* __restrict__ augT) {
  int g = blockIdx.x*256 + threadIdx.x;   // < 49152
  int i = g >> 6, kg = (g >> 4) & 3, l15 = g & 15;
  const float sc1 = 0.14433756729740643f;   // sqrt(1/48)
  const float sc3 = 0.5773502691896258f;    // sqrt(1/3)
  float hw = (l15 < 12) ? log1pf(expf(head_w[l15])) * 0.13608276348795434f : 0.f;
  unsigned short vals[8];
  #pragma unroll
  for (int e = 0; e < 8; e++) {
    int idx = kg*8 + e;
    float v = 0.f;
    if (l15 < 12) {
      if (idx < 16) v = sc1 * q[(size_t)i*192 + l15*16 + idx];
      else if (idx < 28) v = hw * qpts[(size_t)i*144 + l15*12 + (idx-16)];
      else if (idx == 28) v = -0.5f * hw;
      else if (idx == 29) {
        float s2 = 0.f;
        #pragma unroll
        for (int m = 0; m < 12; m++) {
          float d = qpts[(size_t)i*144 + l15*12 + m];
          s2 += d*d;
        }
        v = sc3 * bb[l15] - 0.5f * hw * s2;
      }
    }
    vals[e] = f2bf(v);
  }
  *(us8*)(augT + (size_t)g*8) = *(const us8*)vals;
}

// ---------------------------------------------------------------------------
// K_prep_v: swizzled bf16 B-matrix for k_ov's per-head GEMM. grid 432 x 256
__global__ void k_prep_v(const float* __restrict__ vv, const float* __restrict__ kvpts,
                         unsigned short* __restrict__ Vq) {
  int g = blockIdx.x*256 + threadIdx.x;   // < 110592
  int l15 = g & 15;
  int kg  = (g >> 4) & 3;
  int r2  = g >> 6;          // ((h*3+nt)*24 + ks)
  int ks  = r2 % 24;
  int hn  = r2 / 24;
  int nt  = hn % 3;
  int h   = hn / 3;
  int col = nt*16 + l15;
  unsigned short vals[8];
  #pragma unroll
  for (int e = 0; e < 8; e++) {
    int j = ks*32 + kg*8 + e;
    float v = 0.f;
    if (col < 16)      v = vv[(size_t)j*192 + h*16 + col];
    else if (col < 40) v = kvpts[(size_t)j*432 + h*36 + 12 + (col-16)];
    vals[e] = f2bf(v);
  }
  *(us8*)(Vq + (size_t)g*8) = *(const us8*)vals;
}

// ---------------------------------------------------------------------------
// K_ZPASS: per (i, 64-j chunk): logits MFMA (z read once, transposed into LDS
// on the fly) -> chunk-local softmax -> o_pair PARTIAL MFMA from LDS z^T.
// Writes: unnormalized p_bf, Pp partials, (m,s) per chunk.
// grid (12 jt, 768 i) x 256.
#define ZP 72     // zt row stride (ushorts), mult of 8 for us8 alignment
#define PP 72
__global__ void __launch_bounds__(256) k_zpass(
    const float* __restrict__ z, const unsigned short* __restrict__ Bq,
    const unsigned short* __restrict__ afT, const unsigned short* __restrict__ augT,
    unsigned short* __restrict__ p_bf, float* __restrict__ Pp,
    float* __restrict__ msbuf) {
  __shared__ unsigned short zt[128*ZP];   // z^T tile, bank-staggered
  __shared__ unsigned short p_l[16*PP];
  __shared__ float redm[4][16];
  __shared__ float reds[4][16];
  int jt = blockIdx.x, i = blockIdx.y, t = threadIdx.x;
  int w = t >> 6, l = t & 63, kg = l >> 4, l15 = l & 15;
  const us8* afT8 = (const us8*)afT;
  const us8* augT8 = (const us8*)augT;
  const us8* Bq8 = (const us8*)Bq;
  us8 zero8 = {0,0,0,0,0,0,0,0};

  us8 af[4];
  #pragma unroll
  for (int ks = 0; ks < 4; ks++) af[ks] = afT8[(kg*16 + l15)*4 + ks];
  us8 aug = augT8[((size_t)i*4 + kg)*16 + l15];

  // ---- phase A: logits for this 64-j chunk + transposed z staging
  int jcol = jt*64 + w*16 + l15;
  const float* zr = z + ((size_t)i*NN + jcol)*CZ;
  f32x4 accz = {0.f,0.f,0.f,0.f};
  f32x4 aa0 = {0.f,0.f,0.f,0.f}, aa1 = {0.f,0.f,0.f,0.f}, aa2 = {0.f,0.f,0.f,0.f};
  int js = (w*16 + l15 + kg*16) & 63;   // bank-staggered j slot (stagger = kg)
  #pragma unroll
  for (int ks = 0; ks < 4; ks++) {
    float4 z0 = *(const float4*)(zr + ks*32 + kg*8);
    float4 z1 = *(const float4*)(zr + ks*32 + kg*8 + 4);
    bf16x8 bv;
    bv[0] = (__bf16)z0.x; bv[1] = (__bf16)z0.y; bv[2] = (__bf16)z0.z; bv[3] = (__bf16)z0.w;
    bv[4] = (__bf16)z1.x; bv[5] = (__bf16)z1.y; bv[6] = (__bf16)z1.z; bv[7] = (__bf16)z1.w;
    us8 bu = __builtin_bit_cast(us8, bv);
    #pragma unroll
    for (int e = 0; e < 8; e++)
      zt[(ks*32 + kg*8 + e)*ZP + js] = bu[e];   // zt[c][ (j + 16*((c>>3)&3)) & 63 ]
    accz = __builtin_amdgcn_mfma_f32_16x16x32_bf16(
        __builtin_bit_cast(bf16x8, af[ks]), bv, accz, 0, 0, 0);
  }
  int jtile = jt*4 + w;
  #pragma unroll
  for (int hp = 0; hp < 12; hp++) {
    us8 bqv = Bq8[(size_t)(jtile*12 + hp)*64 + kg*16 + l15];
    us8 sel = (l15 == hp) ? aug : zero8;
    f32x4* dst = (hp < 4) ? &aa0 : (hp < 8) ? &aa1 : &aa2;
    *dst = __builtin_amdgcn_mfma_f32_16x16x32_bf16(
        __builtin_bit_cast(bf16x8, sel), __builtin_bit_cast(bf16x8, bqv), *dst, 0, 0, 0);
  }
  f32x4 lg = (accz + aa0) + (aa1 + aa2);

  // ---- chunk-local softmax over 64 j for h = kg*4+r
  float mr[4];
  #pragma unroll
  for (int r = 0; r < 4; r++) {
    float m = lg[r];
    #pragma unroll
    for (int off = 1; off < 16; off <<= 1) m = fmaxf(m, __shfl_xor(m, off));
    mr[r] = m;
  }
  if (l15 == 0) {
    #pragma unroll
    for (int r = 0; r < 4; r++) redm[w][kg*4+r] = mr[r];
  }
  __syncthreads();
  float er[4], mloc[4];
  float sr[4];
  #pragma unroll
  for (int r = 0; r < 4; r++) {
    int h = kg*4 + r;
    float m = fmaxf(fmaxf(redm[0][h], redm[1][h]), fmaxf(redm[2][h], redm[3][h]));
    mloc[r] = m;
    float e = expf(lg[r] - m);
    er[r] = e;
    float s = e;
    #pragma unroll
    for (int off = 1; off < 16; off <<= 1) s += __shfl_xor(s, off);
    sr[r] = s;
  }
  if (l15 == 0) {
    #pragma unroll
    for (int r = 0; r < 4; r++) reds[w][kg*4+r] = sr[r];
  }
  __syncthreads();
  // p_l rows (h rows; kg==3 writes zeros to rows 12..15)
  #pragma unroll
  for (int r = 0; r < 4; r++) {
    int row = kg*4 + r;
    p_l[row*PP + w*16 + l15] = (kg < 3) ? nf2bf(er[r]) : (unsigned short)0;
  }
  if (w == 0 && l15 == 0 && kg < 3) {
    #pragma unroll
    for (int r = 0; r < 4; r++) {
      int h = kg*4 + r;
      float s_loc = reds[0][h] + reds[1][h] + reds[2][h] + reds[3][h];
      msbuf[((size_t)i*12 + jt)*24 + h]      = mloc[r];
      msbuf[((size_t)i*12 + jt)*24 + 12 + h] = s_loc;
    }
  }
  __syncthreads();

  // unnormalized p dump (combine kernel rescales)
  {
    const us8* pl8 = (const us8*)p_l;   // 9 us8 per row
    us8* pg8 = (us8*)(p_bf + (size_t)i*12*768);
    if (t < 96) {
      int h = t >> 3, c8 = t & 7;
      pg8[h*96 + jt*8 + c8] = pl8[h*9 + c8];
    }
  }

  // ---- phase B: o_pair partial = p_loc @ z_chunk from LDS z^T
  {
    const us8* pl8 = (const us8*)p_l;
    f32x4 acc0 = {0.f,0.f,0.f,0.f}, acc1 = {0.f,0.f,0.f,0.f};
    int c0 = w*32 + l15, c1 = c0 + 16;
    int s0 = (c0 >> 3) & 3, s1 = (c1 >> 3) & 3;
    #pragma unroll
    for (int ks2 = 0; ks2 < 2; ks2++) {
      us8 av = pl8[l15*9 + ks2*4 + kg];
      int j0 = ks2*32 + kg*8;
      us8 b0 = *(const us8*)(zt + (size_t)c0*ZP + ((j0 + s0*16) & 63));
      us8 b1 = *(const us8*)(zt + (size_t)c1*ZP + ((j0 + s1*16) & 63));
      acc0 = __builtin_amdgcn_mfma_f32_16x16x32_bf16(
          __builtin_bit_cast(bf16x8, av), __builtin_bit_cast(bf16x8, b0), acc0, 0, 0, 0);
      acc1 = __builtin_amdgcn_mfma_f32_16x16x32_bf16(
          __builtin_bit_cast(bf16x8, av), __builtin_bit_cast(bf16x8, b1), acc1, 0, 0, 0);
    }
    #pragma unroll
    for (int r = 0; r < 4; r++) {
      int h = kg*4 + r;
      if (h < 12) {
        float* pp = Pp + (((size_t)i*12 + jt)*12 + h)*128;
        pp[c0] = acc0[r];
        pp[c1] = acc1[r];
      }
    }
  }
}

// ---------------------------------------------------------------------------
// K_COMB: flash combine. alpha = e^{m_loc-m}/s; o_pair = sum alpha*Pp;
// normalize p_bf in place. grid 768 x 256.
__global__ void k_comb(const float* __restrict__ Pp, const float* __restrict__ msbuf,
                       unsigned short* __restrict__ p_bf, float* __restrict__ cat) {
  __shared__ float alpha[12][12];   // [h][jt]
  int i = blockIdx.x, t = threadIdx.x;
  if (t < 12) {
    int h = t;
    float ml[12];
    float m = -1e30f;
    #pragma unroll
    for (int jt = 0; jt < 12; jt++) {
      ml[jt] = msbuf[((size_t)i*12 + jt)*24 + h];
      m = fmaxf(m, ml[jt]);
    }
    float s = 0.f;
    float al[12];
    #pragma unroll
    for (int jt = 0; jt < 12; jt++) {
      al[jt] = expf(ml[jt] - m);
      s += msbuf[((size_t)i*12 + jt)*24 + 12 + h] * al[jt];
    }
    float invs = 1.0f / s;
    #pragma unroll
    for (int jt = 0; jt < 12; jt++) alpha[h][jt] = al[jt] * invs;
  }
  __syncthreads();
  // o_pair
  for (int u = t; u < 1536; u += 256) {
    int h = u >> 7, c = u & 127;
    float acc = 0.f;
    #pragma unroll
    for (int jt = 0; jt < 12; jt++)
      acc += Pp[(((size_t)i*12 + jt)*12 + h)*128 + c] * alpha[h][jt];
    cat[(size_t)i*CATC + 576 + h*128 + c] = acc;
  }
  // normalize p for k_ov
  us8* pg8 = (us8*)(p_bf + (size_t)i*12*768);
  for (int u = t; u < 1152; u += 256) {
    int h = u / 96, c8 = u % 96, jt = c8 >> 3;
    float a = alpha[h][jt];
    us8 v = pg8[h*96 + c8];
    #pragma unroll
    for (int e = 0; e < 8; e++) v[e] = nf2bf(bf2f(v[e]) * a);
    pg8[h*96 + c8] = v;
  }
}

// ---------------------------------------------------------------------------
// K4 (MFMA): per-head GEMM P_h[768x768] @ V_h[768x40] -> o and o_pt(+norm).
// grid (48 i-tiles, 12 h) x 256.
__global__ void k_ov(const unsigned short* __restrict__ p_bf,
                     const unsigned short* __restrict__ Vq,
                     const float* __restrict__ rot, const float* __restrict__ trans,
                     float* __restrict__ cat) {
  __shared__ float opt[16][28];
  __shared__ float Rl[16][9];
  __shared__ float Tl[16][3];
  int it = blockIdx.x, h = blockIdx.y, t = threadIdx.x;
  int i0 = it*16;
  int w = t >> 6, l = t & 63, kg = l >> 4, l15 = l & 15;
  if (t < 144) Rl[t/9][t%9] = rot[(size_t)(i0 + t/9)*9 + (t%9)];
  if (t >= 192 && t < 240) {
    int u = t - 192;
    Tl[u/3][u%3] = trans[(size_t)(i0 + u/3)*3 + (u%3)];
  }
  f32x4 acc = {0.f,0.f,0.f,0.f};
  if (w < 3) {
    const unsigned short* prow = p_bf + ((size_t)(i0 + l15)*12 + h)*768 + kg*8;
    const us8* vq = (const us8*)Vq + (size_t)(h*3 + w)*24*64 + kg*16 + l15;
    for (int ks = 0; ks < 24; ks++) {
      us8 av = *(const us8*)(prow + ks*32);
      us8 bv = vq[(size_t)ks*64];
      acc = __builtin_amdgcn_mfma_f32_16x16x32_bf16(
          __builtin_bit_cast(bf16x8, av), __builtin_bit_cast(bf16x8, bv), acc, 0, 0, 0);
    }
  }
  if (w == 0) {
    #pragma unroll
    for (int r = 0; r < 4; r++)
      cat[(size_t)(i0 + kg*4 + r)*CATC + h*16 + l15] = acc[r];
  } else if (w == 1) {
    #pragma unroll
    for (int r = 0; r < 4; r++) opt[kg*4 + r][l15] = acc[r];
  } else if (w == 2) {
    if (l15 < 8) {
      #pragma unroll
      for (int r = 0; r < 4; r++) opt[kg*4 + r][16 + l15] = acc[r];
    }
  }
  __syncthreads();
  if (t < 128) {
    int ip = t >> 3, p = t & 7;
    float x0 = opt[ip][p*3+0] - Tl[ip][0];
    float x1 = opt[ip][p*3+1] - Tl[ip][1];
    float x2 = opt[ip][p*3+2] - Tl[ip][2];
    const float* R = Rl[ip];
    float ox = R[0]*x0 + R[3]*x1 + R[6]*x2;
    float oy = R[1]*x0 + R[4]*x1 + R[7]*x2;
    float oz = R[2]*x0 + R[5]*x1 + R[8]*x2;
    float nrm = sqrtf(ox*ox + oy*oy + oz*oz + 1e-8f);
    float* c = cat + (size_t)(i0 + ip)*CATC;
    int m = h*8 + p;
    c[192 + m] = ox; c[288 + m] = oy; c[384 + m] = oz; c[480 + m] = nrm;
  }
}

// ---------------------------------------------------------------------------
// K6: out = cat @ Wout + bout. ROWS=3/block -> grid 256, x8-unrolled loads.
#define OROWS 3
__global__ void k_out(const float* __restrict__ cat, const float* __restrict__ Wout,
                      const float* __restrict__ bout, float* __restrict__ out) {
  __shared__ float cl[OROWS*CATC];
  int i0 = blockIdx.x*OROWS, t = threadIdx.x;
  for (int idx = t; idx < OROWS*CATC; idx += 384) cl[idx] = cat[(size_t)i0*CATC + idx];
  __syncthreads();
  float acc[OROWS];
  #pragma unroll
  for (int g = 0; g < OROWS; g++) acc[g] = 0.f;
  for (int r = 0; r < CATC; r += 8) {
    float wv[8];
    #pragma unroll
    for (int u = 0; u < 8; u++) wv[u] = Wout[(size_t)(r+u)*384 + t];
    #pragma unroll
    for (int u = 0; u < 8; u++) {
      #pragma unroll
      for (int g = 0; g < OROWS; g++) acc[g] += cl[g*CATC + r + u] * wv[u];
    }
  }
  float bo = bout[t];
  #pragma unroll
  for (int g = 0; g < OROWS; g++) out[(size_t)(i0+g)*384 + t] = acc[g] + bo;
}

// ---------------------------------------------------------------------------
extern "C" void kernel_launch(void* const* d_in, const int* in_sizes, int n_in,
                              void* d_out, int out_size, void* d_ws, size_t ws_size,
                              hipStream_t stream) {
  const float* s      = (const float*)d_in[0];
  const float* z      = (const float*)d_in[1];
  const float* rot    = (const float*)d_in[2];
  const float* trans  = (const float*)d_in[3];
  const float* Wq     = (const float*)d_in[4];
  const float* bq     = (const float*)d_in[5];
  const float* Wkv    = (const float*)d_in[6];
  const float* bkv    = (const float*)d_in[7];
  const float* Wqp    = (const float*)d_in[8];
  const float* bqp    = (const float*)d_in[9];
  const float* Wkvp   = (const float*)d_in[10];
  const float* bkvp   = (const float*)d_in[11];
  const float* Wb     = (const float*)d_in[12];
  const float* bb     = (const float*)d_in[13];
  const float* head_w = (const float*)d_in[14];
  const float* Wout   = (const float*)d_in[15];
  const float* bout   = (const float*)d_in[16];
  float* out = (float*)d_out;

  float* ws    = (float*)d_ws;
  float* q     = ws;                    // 147456
  float* kk    = q     + 147456;        // 147456
  float* vv    = kk    + 147456;        // 147456
  float* qpts  = vv    + 147456;        // 110592
  float* kvpts = qpts  + 110592;        // 331776
  unsigned short* p_bf = (unsigned short*)(kvpts + 331776);  // 7077888 ushorts
  float* cat   = (float*)(p_bf + 7077888);                   // 1622016
  unsigned short* Bq  = (unsigned short*)(cat + 1622016);    // 294912 ushorts
  unsigned short* Vq  = Bq + 294912;                         // 884736 ushorts
  unsigned short* afT = Vq + 884736;                         // 2048 ushorts
  unsigned short* augT= afT + 2048;                          // 393216 ushorts
  float* Pp    = (float*)(augT + 393216);                    // 14155776 floats
  float* msbuf = Pp + 14155776;                              // 221184 floats

  k_proj<<<768, 256, 0, stream>>>(s, rot, trans, Wq, bq, Wkv, bkv, Wqp, bqp,
                                  Wkvp, bkvp, q, kk, vv, qpts, kvpts);
  k_prep<<<48, 256, 0, stream>>>(kk, kvpts, Wb, Bq, afT);
  k_prep_aug<<<192, 256, 0, stream>>>(q, qpts, bb, head_w, augT);
  k_prep_v<<<432, 256, 0, stream>>>(vv, kvpts, Vq);
  k_zpass<<<dim3(12, 768), 256, 0, stream>>>(z, Bq, afT, augT, p_bf, Pp, msbuf);
  k_comb<<<768, 256, 0, stream>>>(Pp, msbuf, p_bf, cat);
  k_ov<<<dim3(48, 12), 256, 0, stream>>>(p_bf, Vq, rot, trans, cat);
  k_out<<<256, 384, 0, stream>>>(cat, Wout, bout, out);
}

// Round 11
// 301.533 us; speedup vs baseline: 1.3136x; 1.2017x over previous
//
#include <hip/hip_runtime.h>
#include <hip/hip_bf16.h>
#include <cmath>

// Problem constants
#define NN 768
#define CS 384
#define CZ 128
#define CH 16
#define HH 12
#define PQ 4
#define PV 8
#define CATC 2112           // H*(CZ+CH+PV*4)

typedef __attribute__((ext_vector_type(8))) __bf16 bf16x8;
typedef __attribute__((ext_vector_type(8))) unsigned short us8;
typedef __attribute__((ext_vector_type(4))) float f32x4;

__device__ __forceinline__ unsigned short f2bf(float f) {
  unsigned int u = __builtin_bit_cast(unsigned int, f);
  u += 0x7FFFu + ((u >> 16) & 1u);   // RNE
  return (unsigned short)(u >> 16);
}
__device__ __forceinline__ float bf2f(unsigned short u) {
  return __builtin_bit_cast(float, ((unsigned int)u) << 16);
}
__device__ __forceinline__ unsigned short nf2bf(float f) {
  __bf16 b = (__bf16)f;
  return __builtin_bit_cast(unsigned short, b);
}

// ---------------------------------------------------------------------------
// K1: projections q,k,v,q_pts,kv_pts (with frame application). grid 768 x 256
__global__ void k_proj(const float* __restrict__ s, const float* __restrict__ rot,
                       const float* __restrict__ trans,
                       const float* __restrict__ Wq, const float* __restrict__ bq,
                       const float* __restrict__ Wkv, const float* __restrict__ bkv,
                       const float* __restrict__ Wqp, const float* __restrict__ bqp,
                       const float* __restrict__ Wkvp, const float* __restrict__ bkvp,
                       float* __restrict__ q, float* __restrict__ kk, float* __restrict__ vv,
                       float* __restrict__ qpts, float* __restrict__ kvpts) {
  __shared__ float srow[CS];
  __shared__ float rawq[144];
  __shared__ float rawkv[432];
  __shared__ float R[9];
  __shared__ float T[3];
  int n = blockIdx.x, t = threadIdx.x;
  for (int u = t; u < CS; u += 256) srow[u] = s[(size_t)n*CS + u];
  if (t < 9) R[t] = rot[(size_t)n*9 + t];
  if (t < 3) T[t] = trans[(size_t)n*3 + t];
  __syncthreads();

  for (int col = t; col < 192; col += 256) {
    float acc = bq[col];
    for (int c = 0; c < CS; c++) acc += srow[c] * Wq[(size_t)c*192 + col];
    q[(size_t)n*192 + col] = acc;
  }
  for (int col = t; col < 384; col += 256) {
    float acc = bkv[col];
    for (int c = 0; c < CS; c++) acc += srow[c] * Wkv[(size_t)c*384 + col];
    int h = col >> 5, u2 = col & 31;
    if (u2 < 16) kk[(size_t)n*192 + h*16 + u2] = acc;
    else         vv[(size_t)n*192 + h*16 + (u2-16)] = acc;
  }
  for (int col = t; col < 144; col += 256) {
    float acc = bqp[col];
    for (int c = 0; c < CS; c++) acc += srow[c] * Wqp[(size_t)c*144 + col];
    rawq[col] = acc;
  }
  for (int col = t; col < 432; col += 256) {
    float acc = bkvp[col];
    for (int c = 0; c < CS; c++) acc += srow[c] * Wkvp[(size_t)c*432 + col];
    rawkv[col] = acc;
  }
  __syncthreads();

  for (int u = t; u < 48*3; u += 256) {
    int m = u / 3, x = u % 3;
    float p0 = rawq[0*48 + m], p1 = rawq[1*48 + m], p2 = rawq[2*48 + m];
    qpts[((size_t)n*48 + m)*3 + x] = R[x*3+0]*p0 + R[x*3+1]*p1 + R[x*3+2]*p2 + T[x];
  }
  for (int u = t; u < 144*3; u += 256) {
    int m = u / 3, x = u % 3;
    float p0 = rawkv[0*144 + m], p1 = rawkv[1*144 + m], p2 = rawkv[2*144 + m];
    kvpts[((size_t)n*144 + m)*3 + x] = R[x*3+0]*p0 + R[x*3+1]*p1 + R[x*3+2]*p2 + T[x];
  }
}

// ---------------------------------------------------------------------------
// K_PREP_ALL: Bq + afT (blocks 0..47), augT (48..239), Vq (240..671).
__global__ void k_prep_all(const float* __restrict__ kk, const float* __restrict__ kvpts,
                           const float* __restrict__ Wb, const float* __restrict__ q,
                           const float* __restrict__ qpts, const float* __restrict__ bb,
                           const float* __restrict__ head_w, const float* __restrict__ vv,
                           unsigned short* __restrict__ Bq, unsigned short* __restrict__ afT,
                           unsigned short* __restrict__ augT, unsigned short* __restrict__ Vq) {
  int b = blockIdx.x, t = threadIdx.x;
  if (b < 48) {
    int jt16 = b;
    for (int u = t; u < 768; u += 256) {
      int hp = u >> 6, kg = (u >> 4) & 3, l15 = u & 15;
      int j = jt16*16 + l15;
      unsigned short vals[8];
      #pragma unroll
      for (int e = 0; e < 8; e++) {
        int cc = kg*8 + e;
        float v;
        if (cc < 16) {
          v = kk[(size_t)j*192 + hp*16 + cc];
        } else if (cc < 28) {
          v = kvpts[(size_t)j*432 + hp*36 + (cc-16)];
        } else if (cc == 28) {
          float s2 = 0.f;
          #pragma unroll
          for (int m = 0; m < 12; m++) {
            float d = kvpts[(size_t)j*432 + hp*36 + m];
            s2 += d*d;
          }
          v = s2;
        } else if (cc == 29) {
          v = 1.0f;
        } else {
          v = 0.f;
        }
        vals[e] = f2bf(v);
      }
      *(us8*)(Bq + ((size_t)(jt16*12 + hp)*64 + kg*16 + l15)*8) = *(const us8*)vals;
    }
    if (b == 0) {
      int kg = t >> 6, l15 = (t >> 2) & 15, ks = t & 3;
      unsigned short vals[8];
      #pragma unroll
      for (int kc = 0; kc < 8; kc++) {
        vals[kc] = (l15 < 12)
          ? f2bf(0.5773502691896258f * Wb[(size_t)(ks*32 + kg*8 + kc)*12 + l15])
          : (unsigned short)0;
      }
      *(us8*)(afT + (size_t)t*8) = *(const us8*)vals;
    }
  } else if (b < 240) {
    int g = (b-48)*256 + t;   // < 49152
    int i = g >> 6, kg = (g >> 4) & 3, l15 = g & 15;
    const float sc1 = 0.14433756729740643f;   // sqrt(1/48)
    const float sc3 = 0.5773502691896258f;    // sqrt(1/3)
    float hw = (l15 < 12) ? log1pf(expf(head_w[l15])) * 0.13608276348795434f : 0.f;
    unsigned short vals[8];
    #pragma unroll
    for (int e = 0; e < 8; e++) {
      int idx = kg*8 + e;
      float v = 0.f;
      if (l15 < 12) {
        if (idx < 16) v = sc1 * q[(size_t)i*192 + l15*16 + idx];
        else if (idx < 28) v = hw * qpts[(size_t)i*144 + l15*12 + (idx-16)];
        else if (idx == 28) v = -0.5f * hw;
        else if (idx == 29) {
          float s2 = 0.f;
          #pragma unroll
          for (int m = 0; m < 12; m++) {
            float d = qpts[(size_t)i*144 + l15*12 + m];
            s2 += d*d;
          }
          v = sc3 * bb[l15] - 0.5f * hw * s2;
        }
      }
      vals[e] = f2bf(v);
    }
    *(us8*)(augT + (size_t)g*8) = *(const us8*)vals;
  } else {
    int g = (b-240)*256 + t;   // < 110592
    int l15 = g & 15;
    int kg  = (g >> 4) & 3;
    int r2  = g >> 6;          // ((h*3+nt)*24 + ks)
    int ks  = r2 % 24;
    int hn  = r2 / 24;
    int nt  = hn % 3;
    int h   = hn / 3;
    int col = nt*16 + l15;
    unsigned short vals[8];
    #pragma unroll
    for (int e = 0; e < 8; e++) {
      int j = ks*32 + kg*8 + e;
      float v = 0.f;
      if (col < 16)      v = vv[(size_t)j*192 + h*16 + col];
      else if (col < 40) v = kvpts[(size_t)j*432 + h*36 + 12 + (col-16)];
      vals[e] = f2bf(v);
    }
    *(us8*)(Vq + (size_t)g*8) = *(const us8*)vals;
  }
}

// ---------------------------------------------------------------------------
// K_ZPASS v2: 128-j chunks, 512 threads / 8 waves.
// Phase A: logits MFMA (z read once, transposed into zt with bank swizzle).
// Chunk-local softmax (cross-8-wave LDS reduce). Phase B: o_pair partial,
// wave w owns c-tile w (8x16 = 128 c), 4 K-steps, no partial combine.
// grid (6 jt, 768 i) x 512.
#define PL2 136   // p_lds row stride in ushorts (us8-aligned, 4-bank stagger)
// zt swizzle: js = (j + 16*((c>>3)&3) + 8*(c&7)) & 127 -> 2 lanes/bank (free)
__global__ void __launch_bounds__(512) k_zpass(
    const float* __restrict__ z, const unsigned short* __restrict__ Bq,
    const unsigned short* __restrict__ afT, const unsigned short* __restrict__ augT,
    unsigned short* __restrict__ p_bf, float* __restrict__ Pp,
    float* __restrict__ msbuf) {
  __shared__ unsigned short zt[128*128];    // 32 KB, z^T tile
  __shared__ unsigned short p_l[16*PL2];    // 4.25 KB
  __shared__ float redm[8][16];
  __shared__ float reds[8][16];
  int jt = blockIdx.x, i = blockIdx.y, t = threadIdx.x;
  int w = t >> 6, l = t & 63, kg = l >> 4, l15 = l & 15;
  const us8* afT8 = (const us8*)afT;
  const us8* augT8 = (const us8*)augT;
  const us8* Bq8 = (const us8*)Bq;
  us8 zero8 = {0,0,0,0,0,0,0,0};

  us8 af[4];
  #pragma unroll
  for (int ks = 0; ks < 4; ks++) af[ks] = afT8[(kg*16 + l15)*4 + ks];
  us8 aug = augT8[((size_t)i*4 + kg)*16 + l15];

  // ---- phase A: logits for this 128-j chunk; stage z^T into LDS
  int jloc = w*16 + l15;                 // 0..127
  int jcol = jt*128 + jloc;
  const float* zr = z + ((size_t)i*NN + jcol)*CZ;
  f32x4 accz = {0.f,0.f,0.f,0.f};
  f32x4 aa0 = {0.f,0.f,0.f,0.f}, aa1 = {0.f,0.f,0.f,0.f}, aa2 = {0.f,0.f,0.f,0.f};
  #pragma unroll
  for (int ks = 0; ks < 4; ks++) {
    float4 z0 = *(const float4*)(zr + ks*32 + kg*8);
    float4 z1 = *(const float4*)(zr + ks*32 + kg*8 + 4);
    bf16x8 bv;
    bv[0] = (__bf16)z0.x; bv[1] = (__bf16)z0.y; bv[2] = (__bf16)z0.z; bv[3] = (__bf16)z0.w;
    bv[4] = (__bf16)z1.x; bv[5] = (__bf16)z1.y; bv[6] = (__bf16)z1.z; bv[7] = (__bf16)z1.w;
    us8 bu = __builtin_bit_cast(us8, bv);
    #pragma unroll
    for (int e = 0; e < 8; e++) {
      int c = ks*32 + kg*8 + e;
      int js = (jloc + 16*((c>>3)&3) + 8*(c&7)) & 127;
      zt[c*128 + js] = bu[e];
    }
    accz = __builtin_amdgcn_mfma_f32_16x16x32_bf16(
        __builtin_bit_cast(bf16x8, af[ks]), bv, accz, 0, 0, 0);
  }
  int jtile = jt*8 + w;
  #pragma unroll
  for (int hp = 0; hp < 12; hp++) {
    us8 bqv = Bq8[(size_t)(jtile*12 + hp)*64 + kg*16 + l15];
    us8 sel = (l15 == hp) ? aug : zero8;
    f32x4* dst = (hp < 4) ? &aa0 : (hp < 8) ? &aa1 : &aa2;
    *dst = __builtin_amdgcn_mfma_f32_16x16x32_bf16(
        __builtin_bit_cast(bf16x8, sel), __builtin_bit_cast(bf16x8, bqv), *dst, 0, 0, 0);
  }
  f32x4 lg = (accz + aa0) + (aa1 + aa2);

  // ---- chunk-local softmax over 128 j for h = kg*4+r
  float mr[4];
  #pragma unroll
  for (int r = 0; r < 4; r++) {
    float m = lg[r];
    #pragma unroll
    for (int off = 1; off < 16; off <<= 1) m = fmaxf(m, __shfl_xor(m, off));
    mr[r] = m;
  }
  if (l15 == 0) {
    #pragma unroll
    for (int r = 0; r < 4; r++) redm[w][kg*4+r] = mr[r];
  }
  __syncthreads();
  float er[4], mloc[4], sr[4];
  #pragma unroll
  for (int r = 0; r < 4; r++) {
    int h = kg*4 + r;
    float m = redm[0][h];
    #pragma unroll
    for (int ww = 1; ww < 8; ww++) m = fmaxf(m, redm[ww][h]);
    mloc[r] = m;
    float e = expf(lg[r] - m);
    er[r] = e;
    float s = e;
    #pragma unroll
    for (int off = 1; off < 16; off <<= 1) s += __shfl_xor(s, off);
    sr[r] = s;
  }
  if (l15 == 0) {
    #pragma unroll
    for (int r = 0; r < 4; r++) reds[w][kg*4+r] = sr[r];
  }
  // write unnormalized p to LDS (rows h; rows 12..15 zeroed by kg==3)
  #pragma unroll
  for (int r = 0; r < 4; r++) {
    int row = kg*4 + r;
    p_l[row*PL2 + jloc] = (kg < 3) ? nf2bf(er[r]) : (unsigned short)0;
  }
  __syncthreads();
  if (w == 0 && l15 == 0 && kg < 3) {
    #pragma unroll
    for (int r = 0; r < 4; r++) {
      int h = kg*4 + r;
      float s_loc = reds[0][h] + reds[1][h] + reds[2][h] + reds[3][h]
                  + reds[4][h] + reds[5][h] + reds[6][h] + reds[7][h];
      msbuf[((size_t)i*6 + jt)*24 + h]      = mloc[r];
      msbuf[((size_t)i*6 + jt)*24 + 12 + h] = s_loc;
    }
  }

  // unnormalized p dump (k_comb rescales in place)
  {
    const us8* pl8 = (const us8*)p_l;   // 17 us8 per row
    us8* pg8 = (us8*)(p_bf + (size_t)i*12*768);
    if (t < 192) {
      int h = t >> 4, c8 = t & 15;
      pg8[h*96 + jt*16 + c8] = pl8[h*17 + c8];
    }
  }

  // ---- phase B: o_pair partial = p_loc @ z_chunk; wave w owns c-tile w
  {
    const us8* pl8 = (const us8*)p_l;
    f32x4 acc = {0.f,0.f,0.f,0.f};
    int c = w*16 + l15;
    int off = 16*((c>>3)&3) + 8*(c&7);
    #pragma unroll
    for (int ks = 0; ks < 4; ks++) {
      us8 av = pl8[l15*17 + ks*4 + kg];
      us8 b = *(const us8*)(zt + c*128 + ((ks*32 + kg*8 + off) & 127));
      acc = __builtin_amdgcn_mfma_f32_16x16x32_bf16(
          __builtin_bit_cast(bf16x8, av), __builtin_bit_cast(bf16x8, b), acc, 0, 0, 0);
    }
    #pragma unroll
    for (int r = 0; r < 4; r++) {
      int h = kg*4 + r;
      if (h < 12)
        Pp[(((size_t)i*6 + jt)*12 + h)*128 + c] = acc[r];
    }
  }
}

// ---------------------------------------------------------------------------
// K_COMB: flash combine over 6 chunks; normalize p_bf in place. grid 768 x 256.
__global__ void k_comb(const float* __restrict__ Pp, const float* __restrict__ msbuf,
                       unsigned short* __restrict__ p_bf, float* __restrict__ cat) {
  __shared__ float alpha[12][6];   // [h][jt]
  int i = blockIdx.x, t = threadIdx.x;
  if (t < 12) {
    int h = t;
    float ml[6];
    float m = -1e30f;
    #pragma unroll
    for (int jt = 0; jt < 6; jt++) {
      ml[jt] = msbuf[((size_t)i*6 + jt)*24 + h];
      m = fmaxf(m, ml[jt]);
    }
    float s = 0.f;
    float al[6];
    #pragma unroll
    for (int jt = 0; jt < 6; jt++) {
      al[jt] = expf(ml[jt] - m);
      s += msbuf[((size_t)i*6 + jt)*24 + 12 + h] * al[jt];
    }
    float invs = 1.0f / s;
    #pragma unroll
    for (int jt = 0; jt < 6; jt++) alpha[h][jt] = al[jt] * invs;
  }
  __syncthreads();
  // o_pair
  for (int u = t; u < 1536; u += 256) {
    int h = u >> 7, c = u & 127;
    float acc = 0.f;
    #pragma unroll
    for (int jt = 0; jt < 6; jt++)
      acc += Pp[(((size_t)i*6 + jt)*12 + h)*128 + c] * alpha[h][jt];
    cat[(size_t)i*CATC + 576 + h*128 + c] = acc;
  }
  // normalize p for k_ov
  us8* pg8 = (us8*)(p_bf + (size_t)i*12*768);
  for (int u = t; u < 1152; u += 256) {
    int h = u / 96, c8 = u % 96, jt = c8 >> 4;
    float a = alpha[h][jt];
    us8 v = pg8[h*96 + c8];
    #pragma unroll
    for (int e = 0; e < 8; e++) v[e] = nf2bf(bf2f(v[e]) * a);
    pg8[h*96 + c8] = v;
  }
}

// ---------------------------------------------------------------------------
// K4 (MFMA): per-head GEMM P_h[768x768] @ V_h[768x40] -> o and o_pt(+norm).
// grid (48 i-tiles, 12 h) x 256.
__global__ void k_ov(const unsigned short* __restrict__ p_bf,
                     const unsigned short* __restrict__ Vq,
                     const float* __restrict__ rot, const float* __restrict__ trans,
                     float* __restrict__ cat) {
  __shared__ float opt[16][28];
  __shared__ float Rl[16][9];
  __shared__ float Tl[16][3];
  int it = blockIdx.x, h = blockIdx.y, t = threadIdx.x;
  int i0 = it*16;
  int w = t >> 6, l = t & 63, kg = l >> 4, l15 = l & 15;
  if (t < 144) Rl[t/9][t%9] = rot[(size_t)(i0 + t/9)*9 + (t%9)];
  if (t >= 192 && t < 240) {
    int u = t - 192;
    Tl[u/3][u%3] = trans[(size_t)(i0 + u/3)*3 + (u%3)];
  }
  f32x4 acc = {0.f,0.f,0.f,0.f};
  if (w < 3) {
    const unsigned short* prow = p_bf + ((size_t)(i0 + l15)*12 + h)*768 + kg*8;
    const us8* vq = (const us8*)Vq + (size_t)(h*3 + w)*24*64 + kg*16 + l15;
    for (int ks = 0; ks < 24; ks++) {
      us8 av = *(const us8*)(prow + ks*32);
      us8 bv = vq[(size_t)ks*64];
      acc = __builtin_amdgcn_mfma_f32_16x16x32_bf16(
          __builtin_bit_cast(bf16x8, av), __builtin_bit_cast(bf16x8, bv), acc, 0, 0, 0);
    }
  }
  if (w == 0) {
    #pragma unroll
    for (int r = 0; r < 4; r++)
      cat[(size_t)(i0 + kg*4 + r)*CATC + h*16 + l15] = acc[r];
  } else if (w == 1) {
    #pragma unroll
    for (int r = 0; r < 4; r++) opt[kg*4 + r][l15] = acc[r];
  } else if (w == 2) {
    if (l15 < 8) {
      #pragma unroll
      for (int r = 0; r < 4; r++) opt[kg*4 + r][16 + l15] = acc[r];
    }
  }
  __syncthreads();
  if (t < 128) {
    int ip = t >> 3, p = t & 7;
    float x0 = opt[ip][p*3+0] - Tl[ip][0];
    float x1 = opt[ip][p*3+1] - Tl[ip][1];
    float x2 = opt[ip][p*3+2] - Tl[ip][2];
    const float* R = Rl[ip];
    float ox = R[0]*x0 + R[3]*x1 + R[6]*x2;
    float oy = R[1]*x0 + R[4]*x1 + R[7]*x2;
    float oz = R[2]*x0 + R[5]*x1 + R[8]*x2;
    float nrm = sqrtf(ox*ox + oy*oy + oz*oz + 1e-8f);
    float* c = cat + (size_t)(i0 + ip)*CATC;
    int m = h*8 + p;
    c[192 + m] = ox; c[288 + m] = oy; c[384 + m] = oz; c[480 + m] = nrm;
  }
}

// ---------------------------------------------------------------------------
// K6: out = cat @ Wout + bout. ROWS=3/block -> grid 256, x8-unrolled loads.
#define OROWS 3
__global__ void k_out(const float* __restrict__ cat, const float* __restrict__ Wout,
                      const float* __restrict__ bout, float* __restrict__ out) {
  __shared__ float cl[OROWS*CATC];
  int i0 = blockIdx.x*OROWS, t = threadIdx.x;
  for (int idx = t; idx < OROWS*CATC; idx += 384) cl[idx] = cat[(size_t)i0*CATC + idx];
  __syncthreads();
  float acc[OROWS];
  #pragma unroll
  for (int g = 0; g < OROWS; g++) acc[g] = 0.f;
  for (int r = 0; r < CATC; r += 8) {
    float wv[8];
    #pragma unroll
    for (int u = 0; u < 8; u++) wv[u] = Wout[(size_t)(r+u)*384 + t];
    #pragma unroll
    for (int u = 0; u < 8; u++) {
      #pragma unroll
      for (int g = 0; g < OROWS; g++) acc[g] += cl[g*CATC + r + u] * wv[u];
    }
  }
  float bo = bout[t];
  #pragma unroll
  for (int g = 0; g < OROWS; g++) out[(size_t)(i0+g)*384 + t] = acc[g] + bo;
}

// ---------------------------------------------------------------------------
extern "C" void kernel_launch(void* const* d_in, const int* in_sizes, int n_in,
                              void* d_out, int out_size, void* d_ws, size_t ws_size,
                              hipStream_t stream) {
  const float* s      = (const float*)d_in[0];
  const float* z      = (const float*)d_in[1];
  const float* rot    = (const float*)d_in[2];
  const float* trans  = (const float*)d_in[3];
  const float* Wq     = (const float*)d_in[4];
  const float* bq     = (const float*)d_in[5];
  const float* Wkv    = (const float*)d_in[6];
  const float* bkv    = (const float*)d_in[7];
  const float* Wqp    = (const float*)d_in[8];
  const float* bqp    = (const float*)d_in[9];
  const float* Wkvp   = (const float*)d_in[10];
  const float* bkvp   = (const float*)d_in[11];
  const float* Wb     = (const float*)d_in[12];
  const float* bb     = (const float*)d_in[13];
  const float* head_w = (const float*)d_in[14];
  const float* Wout   = (const float*)d_in[15];
  const float* bout   = (const float*)d_in[16];
  float* out = (float*)d_out;

  float* ws    = (float*)d_ws;
  float* q     = ws;                    // 147456
  float* kk    = q     + 147456;        // 147456
  float* vv    = kk    + 147456;        // 147456
  float* qpts  = vv    + 147456;        // 110592
  float* kvpts = qpts  + 110592;        // 331776
  unsigned short* p_bf = (unsigned short*)(kvpts + 331776);  // 7077888 ushorts
  float* cat   = (float*)(p_bf + 7077888);                   // 1622016
  unsigned short* Bq  = (unsigned short*)(cat + 1622016);    // 294912 ushorts
  unsigned short* Vq  = Bq + 294912;                         // 884736 ushorts
  unsigned short* afT = Vq + 884736;                         // 2048 ushorts
  unsigned short* augT= afT + 2048;                          // 393216 ushorts
  float* Pp    = (float*)(augT + 393216);                    // 7077888 floats
  float* msbuf = Pp + 7077888;                               // 110592 floats

  k_proj<<<768, 256, 0, stream>>>(s, rot, trans, Wq, bq, Wkv, bkv, Wqp, bqp,
                                  Wkvp, bkvp, q, kk, vv, qpts, kvpts);
  k_prep_all<<<672, 256, 0, stream>>>(kk, kvpts, Wb, q, qpts, bb, head_w, vv,
                                      Bq, afT, augT, Vq);
  k_zpass<<<dim3(6, 768), 512, 0, stream>>>(z, Bq, afT, augT, p_bf, Pp, msbuf);
  k_comb<<<768, 256, 0, stream>>>(Pp, msbuf, p_bf, cat);
  k_ov<<<dim3(48, 12), 256, 0, stream>>>(p_bf, Vq, rot, trans, cat);
  k_out<<<256, 384, 0, stream>>>(cat, Wout, bout, out);
}

// Round 12
// 292.189 us; speedup vs baseline: 1.3556x; 1.0320x over previous
//
#include <hip/hip_runtime.h>
#include <hip/hip_bf16.h>
#include <cmath>

// Problem constants
#define NN 768
#define CS 384
#define CZ 128
#define CH 16
#define HH 12
#define PQ 4
#define PV 8
#define CATC 2112           // H*(CZ+CH+PV*4)

typedef __attribute__((ext_vector_type(8))) __bf16 bf16x8;
typedef __attribute__((ext_vector_type(8))) unsigned short us8;
typedef __attribute__((ext_vector_type(4))) float f32x4;

__device__ __forceinline__ unsigned short f2bf(float f) {
  unsigned int u = __builtin_bit_cast(unsigned int, f);
  u += 0x7FFFu + ((u >> 16) & 1u);   // RNE
  return (unsigned short)(u >> 16);
}
__device__ __forceinline__ float bf2f(unsigned short u) {
  return __builtin_bit_cast(float, ((unsigned int)u) << 16);
}
__device__ __forceinline__ unsigned short nf2bf(float f) {
  __bf16 b = (__bf16)f;
  return __builtin_bit_cast(unsigned short, b);
}

// ---------------------------------------------------------------------------
// K_PREP_W: pack [Wq|Wkv|Wqp|Wkvp] -> Wall[384][1152] fp32; Wout -> bf16.
// flat grid 4896 x 256.
__global__ void k_prep_w(const float* __restrict__ Wq, const float* __restrict__ Wkv,
                         const float* __restrict__ Wqp, const float* __restrict__ Wkvp,
                         const float* __restrict__ Wout,
                         float* __restrict__ Wall, unsigned short* __restrict__ Wout_bf) {
  int g = blockIdx.x*256 + threadIdx.x;
  if (g < 442368) {
    int c = g / 1152, col = g % 1152;
    float v;
    if (col < 192)      v = Wq[(size_t)c*192 + col];
    else if (col < 576) v = Wkv[(size_t)c*384 + (col-192)];
    else if (col < 720) v = Wqp[(size_t)c*144 + (col-576)];
    else                v = Wkvp[(size_t)c*432 + (col-720)];
    Wall[g] = v;
  } else {
    int g2 = g - 442368;
    if (g2 < 811008) Wout_bf[g2] = nf2bf(Wout[g2]);
  }
}

// ---------------------------------------------------------------------------
// K_PROJG: projection GEMM, 8 i-rows/block, fp32, grid 96 x 384.
// Thread owns cols {t, t+384, t+768}; Wall streamed coalescedly; s-tile in
// LDS read as broadcast float4. Frame application in-block epilogue.
__global__ void __launch_bounds__(384) k_projg(
    const float* __restrict__ s, const float* __restrict__ Wall,
    const float* __restrict__ rot, const float* __restrict__ trans,
    const float* __restrict__ bq, const float* __restrict__ bkv,
    const float* __restrict__ bqp, const float* __restrict__ bkvp,
    float* __restrict__ q, float* __restrict__ kk, float* __restrict__ vv,
    float* __restrict__ qpts, float* __restrict__ kvpts) {
  __shared__ float sl[8][384];
  __shared__ float raw[8][576];    // [rawq(144)|rawkv(432)] per i, bias included
  __shared__ float Rl[8][9];
  __shared__ float Tl[8][3];
  int i0 = blockIdx.x*8, t = threadIdx.x;
  #pragma unroll
  for (int k = 0; k < 8; k++) sl[k][t] = s[(size_t)(i0+k)*CS + t];
  if (t < 72) Rl[t/9][t%9] = rot[(size_t)i0*9 + t];
  else if (t < 96) { int u = t-72; Tl[u/3][u%3] = trans[(size_t)i0*3 + u]; }
  __syncthreads();

  float a0[8], a1[8], a2[8];
  #pragma unroll
  for (int g = 0; g < 8; g++) { a0[g]=0.f; a1[g]=0.f; a2[g]=0.f; }
  {
    const float* w0 = Wall + t;
    const float* w1 = Wall + 384 + t;
    const float* w2 = Wall + 768 + t;
    #pragma unroll 4
    for (int c4 = 0; c4 < 96; c4++) {
      float4 sv[8];
      #pragma unroll
      for (int g = 0; g < 8; g++) sv[g] = *(const float4*)&sl[g][c4*4];
      #pragma unroll
      for (int e = 0; e < 4; e++) {
        int c = c4*4 + e;
        float wv0 = w0[(size_t)c*1152];
        float wv1 = w1[(size_t)c*1152];
        float wv2 = w2[(size_t)c*1152];
        #pragma unroll
        for (int g = 0; g < 8; g++) {
          float svv = (e==0)?sv[g].x:(e==1)?sv[g].y:(e==2)?sv[g].z:sv[g].w;
          a0[g] += svv*wv0; a1[g] += svv*wv1; a2[g] += svv*wv2;
        }
      }
    }
  }
  // scatter col0 = t
  if (t < 192) {
    float b = bq[t];
    #pragma unroll
    for (int g = 0; g < 8; g++) q[(size_t)(i0+g)*192 + t] = a0[g] + b;
  } else {
    int cc = t - 192;          // 0..191 (first half of kv)
    float b = bkv[cc];
    int h = cc >> 5, u2 = cc & 31;
    #pragma unroll
    for (int g = 0; g < 8; g++) {
      float v = a0[g] + b;
      if (u2 < 16) kk[(size_t)(i0+g)*192 + h*16 + u2] = v;
      else         vv[(size_t)(i0+g)*192 + h*16 + (u2-16)] = v;
    }
  }
  // scatter col1 = t+384
  if (t < 192) {
    int cc = t + 192;          // second half of kv
    float b = bkv[cc];
    int h = cc >> 5, u2 = cc & 31;
    #pragma unroll
    for (int g = 0; g < 8; g++) {
      float v = a1[g] + b;
      if (u2 < 16) kk[(size_t)(i0+g)*192 + h*16 + u2] = v;
      else         vv[(size_t)(i0+g)*192 + h*16 + (u2-16)] = v;
    }
  } else if (t < 336) {
    int m = t - 192;           // rawq 0..143
    float b = bqp[m];
    #pragma unroll
    for (int g = 0; g < 8; g++) raw[g][m] = a1[g] + b;
  } else {
    int m2 = t - 336;          // rawkv 0..47
    float b = bkvp[m2];
    #pragma unroll
    for (int g = 0; g < 8; g++) raw[g][144 + m2] = a1[g] + b;
  }
  // scatter col2 = t+768 -> rawkv 48..431
  {
    int m2 = t + 48;
    float b = bkvp[m2];
    #pragma unroll
    for (int g = 0; g < 8; g++) raw[g][144 + m2] = a2[g] + b;
  }
  __syncthreads();

  // frame application: 8 i x (48 qp + 144 kvp) points
  for (int u = t; u < 8*192; u += 384) {
    int g = u / 192, pt = u % 192;
    const float* R = Rl[g];
    const float* T = Tl[g];
    if (pt < 48) {
      float p0 = raw[g][pt], p1 = raw[g][48+pt], p2 = raw[g][96+pt];
      float* d = qpts + ((size_t)(i0+g)*48 + pt)*3;
      d[0] = R[0]*p0 + R[1]*p1 + R[2]*p2 + T[0];
      d[1] = R[3]*p0 + R[4]*p1 + R[5]*p2 + T[1];
      d[2] = R[6]*p0 + R[7]*p1 + R[8]*p2 + T[2];
    } else {
      int m = pt - 48;
      float p0 = raw[g][144+m], p1 = raw[g][288+m], p2 = raw[g][432+m];
      float* d = kvpts + ((size_t)(i0+g)*144 + m)*3;
      d[0] = R[0]*p0 + R[1]*p1 + R[2]*p2 + T[0];
      d[1] = R[3]*p0 + R[4]*p1 + R[5]*p2 + T[1];
      d[2] = R[6]*p0 + R[7]*p1 + R[8]*p2 + T[2];
    }
  }
}

// ---------------------------------------------------------------------------
// K_PREP_ALL: Bq + afT (blocks 0..47), augT (48..239), Vq (240..671).
__global__ void k_prep_all(const float* __restrict__ kk, const float* __restrict__ kvpts,
                           const float* __restrict__ Wb, const float* __restrict__ q,
                           const float* __restrict__ qpts, const float* __restrict__ bb,
                           const float* __restrict__ head_w, const float* __restrict__ vv,
                           unsigned short* __restrict__ Bq, unsigned short* __restrict__ afT,
                           unsigned short* __restrict__ augT, unsigned short* __restrict__ Vq) {
  int b = blockIdx.x, t = threadIdx.x;
  if (b < 48) {
    int jt16 = b;
    for (int u = t; u < 768; u += 256) {
      int hp = u >> 6, kg = (u >> 4) & 3, l15 = u & 15;
      int j = jt16*16 + l15;
      unsigned short vals[8];
      #pragma unroll
      for (int e = 0; e < 8; e++) {
        int cc = kg*8 + e;
        float v;
        if (cc < 16) {
          v = kk[(size_t)j*192 + hp*16 + cc];
        } else if (cc < 28) {
          v = kvpts[(size_t)j*432 + hp*36 + (cc-16)];
        } else if (cc == 28) {
          float s2 = 0.f;
          #pragma unroll
          for (int m = 0; m < 12; m++) {
            float d = kvpts[(size_t)j*432 + hp*36 + m];
            s2 += d*d;
          }
          v = s2;
        } else if (cc == 29) {
          v = 1.0f;
        } else {
          v = 0.f;
        }
        vals[e] = f2bf(v);
      }
      *(us8*)(Bq + ((size_t)(jt16*12 + hp)*64 + kg*16 + l15)*8) = *(const us8*)vals;
    }
    if (b == 0) {
      int kg = t >> 6, l15 = (t >> 2) & 15, ks = t & 3;
      unsigned short vals[8];
      #pragma unroll
      for (int kc = 0; kc < 8; kc++) {
        vals[kc] = (l15 < 12)
          ? f2bf(0.5773502691896258f * Wb[(size_t)(ks*32 + kg*8 + kc)*12 + l15])
          : (unsigned short)0;
      }
      *(us8*)(afT + (size_t)t*8) = *(const us8*)vals;
    }
  } else if (b < 240) {
    int g = (b-48)*256 + t;   // < 49152
    int i = g >> 6, kg = (g >> 4) & 3, l15 = g & 15;
    const float sc1 = 0.14433756729740643f;   // sqrt(1/48)
    const float sc3 = 0.5773502691896258f;    // sqrt(1/3)
    float hw = (l15 < 12) ? log1pf(expf(head_w[l15])) * 0.13608276348795434f : 0.f;
    unsigned short vals[8];
    #pragma unroll
    for (int e = 0; e < 8; e++) {
      int idx = kg*8 + e;
      float v = 0.f;
      if (l15 < 12) {
        if (idx < 16) v = sc1 * q[(size_t)i*192 + l15*16 + idx];
        else if (idx < 28) v = hw * qpts[(size_t)i*144 + l15*12 + (idx-16)];
        else if (idx == 28) v = -0.5f * hw;
        else if (idx == 29) {
          float s2 = 0.f;
          #pragma unroll
          for (int m = 0; m < 12; m++) {
            float d = qpts[(size_t)i*144 + l15*12 + m];
            s2 += d*d;
          }
          v = sc3 * bb[l15] - 0.5f * hw * s2;
        }
      }
      vals[e] = f2bf(v);
    }
    *(us8*)(augT + (size_t)g*8) = *(const us8*)vals;
  } else {
    int g = (b-240)*256 + t;   // < 110592
    int l15 = g & 15;
    int kg  = (g >> 4) & 3;
    int r2  = g >> 6;          // ((h*3+nt)*24 + ks)
    int ks  = r2 % 24;
    int hn  = r2 / 24;
    int nt  = hn % 3;
    int h   = hn / 3;
    int col = nt*16 + l15;
    unsigned short vals[8];
    #pragma unroll
    for (int e = 0; e < 8; e++) {
      int j = ks*32 + kg*8 + e;
      float v = 0.f;
      if (col < 16)      v = vv[(size_t)j*192 + h*16 + col];
      else if (col < 40) v = kvpts[(size_t)j*432 + h*36 + 12 + (col-16)];
      vals[e] = f2bf(v);
    }
    *(us8*)(Vq + (size_t)g*8) = *(const us8*)vals;
  }
}

// ---------------------------------------------------------------------------
// K_ZPASS v2: 128-j chunks, 512 threads / 8 waves. grid (6 jt, 768 i) x 512.
#define PL2 136   // p_lds row stride in ushorts
// zt swizzle: js = (j + 16*((c>>3)&3) + 8*(c&7)) & 127 -> 2 lanes/bank (free)
__global__ void __launch_bounds__(512) k_zpass(
    const float* __restrict__ z, const unsigned short* __restrict__ Bq,
    const unsigned short* __restrict__ afT, const unsigned short* __restrict__ augT,
    unsigned short* __restrict__ p_bf, float* __restrict__ Pp,
    float* __restrict__ msbuf) {
  __shared__ unsigned short zt[128*128];    // 32 KB, z^T tile
  __shared__ unsigned short p_l[16*PL2];    // 4.25 KB
  __shared__ float redm[8][16];
  __shared__ float reds[8][16];
  int jt = blockIdx.x, i = blockIdx.y, t = threadIdx.x;
  int w = t >> 6, l = t & 63, kg = l >> 4, l15 = l & 15;
  const us8* afT8 = (const us8*)afT;
  const us8* augT8 = (const us8*)augT;
  const us8* Bq8 = (const us8*)Bq;
  us8 zero8 = {0,0,0,0,0,0,0,0};

  us8 af[4];
  #pragma unroll
  for (int ks = 0; ks < 4; ks++) af[ks] = afT8[(kg*16 + l15)*4 + ks];
  us8 aug = augT8[((size_t)i*4 + kg)*16 + l15];

  // ---- phase A: logits for this 128-j chunk; stage z^T into LDS
  int jloc = w*16 + l15;                 // 0..127
  int jcol = jt*128 + jloc;
  const float* zr = z + ((size_t)i*NN + jcol)*CZ;
  f32x4 accz = {0.f,0.f,0.f,0.f};
  f32x4 aa0 = {0.f,0.f,0.f,0.f}, aa1 = {0.f,0.f,0.f,0.f}, aa2 = {0.f,0.f,0.f,0.f};
  #pragma unroll
  for (int ks = 0; ks < 4; ks++) {
    float4 z0 = *(const float4*)(zr + ks*32 + kg*8);
    float4 z1 = *(const float4*)(zr + ks*32 + kg*8 + 4);
    bf16x8 bv;
    bv[0] = (__bf16)z0.x; bv[1] = (__bf16)z0.y; bv[2] = (__bf16)z0.z; bv[3] = (__bf16)z0.w;
    bv[4] = (__bf16)z1.x; bv[5] = (__bf16)z1.y; bv[6] = (__bf16)z1.z; bv[7] = (__bf16)z1.w;
    us8 bu = __builtin_bit_cast(us8, bv);
    #pragma unroll
    for (int e = 0; e < 8; e++) {
      int c = ks*32 + kg*8 + e;
      int js = (jloc + 16*((c>>3)&3) + 8*(c&7)) & 127;
      zt[c*128 + js] = bu[e];
    }
    accz = __builtin_amdgcn_mfma_f32_16x16x32_bf16(
        __builtin_bit_cast(bf16x8, af[ks]), bv, accz, 0, 0, 0);
  }
  int jtile = jt*8 + w;
  #pragma unroll
  for (int hp = 0; hp < 12; hp++) {
    us8 bqv = Bq8[(size_t)(jtile*12 + hp)*64 + kg*16 + l15];
    us8 sel = (l15 == hp) ? aug : zero8;
    f32x4* dst = (hp < 4) ? &aa0 : (hp < 8) ? &aa1 : &aa2;
    *dst = __builtin_amdgcn_mfma_f32_16x16x32_bf16(
        __builtin_bit_cast(bf16x8, sel), __builtin_bit_cast(bf16x8, bqv), *dst, 0, 0, 0);
  }
  f32x4 lg = (accz + aa0) + (aa1 + aa2);

  // ---- chunk-local softmax over 128 j for h = kg*4+r
  float mr[4];
  #pragma unroll
  for (int r = 0; r < 4; r++) {
    float m = lg[r];
    #pragma unroll
    for (int off = 1; off < 16; off <<= 1) m = fmaxf(m, __shfl_xor(m, off));
    mr[r] = m;
  }
  if (l15 == 0) {
    #pragma unroll
    for (int r = 0; r < 4; r++) redm[w][kg*4+r] = mr[r];
  }
  __syncthreads();
  float er[4], mloc[4], sr[4];
  #pragma unroll
  for (int r = 0; r < 4; r++) {
    int h = kg*4 + r;
    float m = redm[0][h];
    #pragma unroll
    for (int ww = 1; ww < 8; ww++) m = fmaxf(m, redm[ww][h]);
    mloc[r] = m;
    float e = expf(lg[r] - m);
    er[r] = e;
    float s = e;
    #pragma unroll
    for (int off = 1; off < 16; off <<= 1) s += __shfl_xor(s, off);
    sr[r] = s;
  }
  if (l15 == 0) {
    #pragma unroll
    for (int r = 0; r < 4; r++) reds[w][kg*4+r] = sr[r];
  }
  // write unnormalized p to LDS (rows h; rows 12..15 zeroed by kg==3)
  #pragma unroll
  for (int r = 0; r < 4; r++) {
    int row = kg*4 + r;
    p_l[row*PL2 + jloc] = (kg < 3) ? nf2bf(er[r]) : (unsigned short)0;
  }
  __syncthreads();
  if (w == 0 && l15 == 0 && kg < 3) {
    #pragma unroll
    for (int r = 0; r < 4; r++) {
      int h = kg*4 + r;
      float s_loc = reds[0][h] + reds[1][h] + reds[2][h] + reds[3][h]
                  + reds[4][h] + reds[5][h] + reds[6][h] + reds[7][h];
      msbuf[((size_t)i*6 + jt)*24 + h]      = mloc[r];
      msbuf[((size_t)i*6 + jt)*24 + 12 + h] = s_loc;
    }
  }

  // unnormalized p dump (k_comb rescales in place)
  {
    const us8* pl8 = (const us8*)p_l;   // 17 us8 per row
    us8* pg8 = (us8*)(p_bf + (size_t)i*12*768);
    if (t < 192) {
      int h = t >> 4, c8 = t & 15;
      pg8[h*96 + jt*16 + c8] = pl8[h*17 + c8];
    }
  }

  // ---- phase B: o_pair partial = p_loc @ z_chunk; wave w owns c-tile w
  {
    const us8* pl8 = (const us8*)p_l;
    f32x4 acc = {0.f,0.f,0.f,0.f};
    int c = w*16 + l15;
    int off = 16*((c>>3)&3) + 8*(c&7);
    #pragma unroll
    for (int ks = 0; ks < 4; ks++) {
      us8 av = pl8[l15*17 + ks*4 + kg];
      us8 b = *(const us8*)(zt + c*128 + ((ks*32 + kg*8 + off) & 127));
      acc = __builtin_amdgcn_mfma_f32_16x16x32_bf16(
          __builtin_bit_cast(bf16x8, av), __builtin_bit_cast(bf16x8, b), acc, 0, 0, 0);
    }
    #pragma unroll
    for (int r = 0; r < 4; r++) {
      int h = kg*4 + r;
      if (h < 12)
        Pp[(((size_t)i*6 + jt)*12 + h)*128 + c] = acc[r];
    }
  }
}

// ---------------------------------------------------------------------------
// K_COMB: flash combine over 6 chunks; normalize p_bf in place. grid 768 x 256.
__global__ void k_comb(const float* __restrict__ Pp, const float* __restrict__ msbuf,
                       unsigned short* __restrict__ p_bf, float* __restrict__ cat) {
  __shared__ float alpha[12][6];   // [h][jt]
  int i = blockIdx.x, t = threadIdx.x;
  if (t < 12) {
    int h = t;
    float ml[6];
    float m = -1e30f;
    #pragma unroll
    for (int jt = 0; jt < 6; jt++) {
      ml[jt] = msbuf[((size_t)i*6 + jt)*24 + h];
      m = fmaxf(m, ml[jt]);
    }
    float s = 0.f;
    float al[6];
    #pragma unroll
    for (int jt = 0; jt < 6; jt++) {
      al[jt] = expf(ml[jt] - m);
      s += msbuf[((size_t)i*6 + jt)*24 + 12 + h] * al[jt];
    }
    float invs = 1.0f / s;
    #pragma unroll
    for (int jt = 0; jt < 6; jt++) alpha[h][jt] = al[jt] * invs;
  }
  __syncthreads();
  // o_pair
  for (int u = t; u < 1536; u += 256) {
    int h = u >> 7, c = u & 127;
    float acc = 0.f;
    #pragma unroll
    for (int jt = 0; jt < 6; jt++)
      acc += Pp[(((size_t)i*6 + jt)*12 + h)*128 + c] * alpha[h][jt];
    cat[(size_t)i*CATC + 576 + h*128 + c] = acc;
  }
  // normalize p for k_ov
  us8* pg8 = (us8*)(p_bf + (size_t)i*12*768);
  for (int u = t; u < 1152; u += 256) {
    int h = u / 96, c8 = u % 96, jt = c8 >> 4;
    float a = alpha[h][jt];
    us8 v = pg8[h*96 + c8];
    #pragma unroll
    for (int e = 0; e < 8; e++) v[e] = nf2bf(bf2f(v[e]) * a);
    pg8[h*96 + c8] = v;
  }
}

// ---------------------------------------------------------------------------
// K4 (MFMA): per-head GEMM P_h[768x768] @ V_h[768x40] -> o and o_pt(+norm).
// grid (48 i-tiles, 12 h) x 256.
__global__ void k_ov(const unsigned short* __restrict__ p_bf,
                     const unsigned short* __restrict__ Vq,
                     const float* __restrict__ rot, const float* __restrict__ trans,
                     float* __restrict__ cat) {
  __shared__ float opt[16][28];
  __shared__ float Rl[16][9];
  __shared__ float Tl[16][3];
  int it = blockIdx.x, h = blockIdx.y, t = threadIdx.x;
  int i0 = it*16;
  int w = t >> 6, l = t & 63, kg = l >> 4, l15 = l & 15;
  if (t < 144) Rl[t/9][t%9] = rot[(size_t)(i0 + t/9)*9 + (t%9)];
  if (t >= 192 && t < 240) {
    int u = t - 192;
    Tl[u/3][u%3] = trans[(size_t)(i0 + u/3)*3 + (u%3)];
  }
  f32x4 acc = {0.f,0.f,0.f,0.f};
  if (w < 3) {
    const unsigned short* prow = p_bf + ((size_t)(i0 + l15)*12 + h)*768 + kg*8;
    const us8* vq = (const us8*)Vq + (size_t)(h*3 + w)*24*64 + kg*16 + l15;
    for (int ks = 0; ks < 24; ks++) {
      us8 av = *(const us8*)(prow + ks*32);
      us8 bv = vq[(size_t)ks*64];
      acc = __builtin_amdgcn_mfma_f32_16x16x32_bf16(
          __builtin_bit_cast(bf16x8, av), __builtin_bit_cast(bf16x8, bv), acc, 0, 0, 0);
    }
  }
  if (w == 0) {
    #pragma unroll
    for (int r = 0; r < 4; r++)
      cat[(size_t)(i0 + kg*4 + r)*CATC + h*16 + l15] = acc[r];
  } else if (w == 1) {
    #pragma unroll
    for (int r = 0; r < 4; r++) opt[kg*4 + r][l15] = acc[r];
  } else if (w == 2) {
    if (l15 < 8) {
      #pragma unroll
      for (int r = 0; r < 4; r++) opt[kg*4 + r][16 + l15] = acc[r];
    }
  }
  __syncthreads();
  if (t < 128) {
    int ip = t >> 3, p = t & 7;
    float x0 = opt[ip][p*3+0] - Tl[ip][0];
    float x1 = opt[ip][p*3+1] - Tl[ip][1];
    float x2 = opt[ip][p*3+2] - Tl[ip][2];
    const float* R = Rl[ip];
    float ox = R[0]*x0 + R[3]*x1 + R[6]*x2;
    float oy = R[1]*x0 + R[4]*x1 + R[7]*x2;
    float oz = R[2]*x0 + R[5]*x1 + R[8]*x2;
    float nrm = sqrtf(ox*ox + oy*oy + oz*oz + 1e-8f);
    float* c = cat + (size_t)(i0 + ip)*CATC;
    int m = h*8 + p;
    c[192 + m] = ox; c[288 + m] = oy; c[384 + m] = oz; c[480 + m] = nrm;
  }
}

// ---------------------------------------------------------------------------
// K6: out = cat @ Wout + bout, Wout in bf16 (halves L2 traffic).
// ROWS=3/block -> grid 256, x8-unrolled loads.
#define OROWS 3
__global__ void k_out(const float* __restrict__ cat, const unsigned short* __restrict__ Wout_bf,
                      const float* __restrict__ bout, float* __restrict__ out) {
  __shared__ float cl[OROWS*CATC];
  int i0 = blockIdx.x*OROWS, t = threadIdx.x;
  for (int idx = t; idx < OROWS*CATC; idx += 384) cl[idx] = cat[(size_t)i0*CATC + idx];
  __syncthreads();
  float acc[OROWS];
  #pragma unroll
  for (int g = 0; g < OROWS; g++) acc[g] = 0.f;
  for (int r = 0; r < CATC; r += 8) {
    float wv[8];
    #pragma unroll
    for (int u = 0; u < 8; u++) wv[u] = bf2f(Wout_bf[(size_t)(r+u)*384 + t]);
    #pragma unroll
    for (int u = 0; u < 8; u++) {
      #pragma unroll
      for (int g = 0; g < OROWS; g++) acc[g] += cl[g*CATC + r + u] * wv[u];
    }
  }
  float bo = bout[t];
  #pragma unroll
  for (int g = 0; g < OROWS; g++) out[(size_t)(i0+g)*384 + t] = acc[g] + bo;
}

// ---------------------------------------------------------------------------
extern "C" void kernel_launch(void* const* d_in, const int* in_sizes, int n_in,
                              void* d_out, int out_size, void* d_ws, size_t ws_size,
                              hipStream_t stream) {
  const float* s      = (const float*)d_in[0];
  const float* z      = (const float*)d_in[1];
  const float* rot    = (const float*)d_in[2];
  const float* trans  = (const float*)d_in[3];
  const float* Wq     = (const float*)d_in[4];
  const float* bq     = (const float*)d_in[5];
  const float* Wkv    = (const float*)d_in[6];
  const float* bkv    = (const float*)d_in[7];
  const float* Wqp    = (const float*)d_in[8];
  const float* bqp    = (const float*)d_in[9];
  const float* Wkvp   = (const float*)d_in[10];
  const float* bkvp   = (const float*)d_in[11];
  const float* Wb     = (const float*)d_in[12];
  const float* bb     = (const float*)d_in[13];
  const float* head_w = (const float*)d_in[14];
  const float* Wout   = (const float*)d_in[15];
  const float* bout   = (const float*)d_in[16];
  float* out = (float*)d_out;

  float* ws    = (float*)d_ws;
  float* q     = ws;                    // 147456
  float* kk    = q     + 147456;        // 147456
  float* vv    = kk    + 147456;        // 147456
  float* qpts  = vv    + 147456;        // 110592
  float* kvpts = qpts  + 110592;        // 331776
  unsigned short* p_bf = (unsigned short*)(kvpts + 331776);  // 7077888 ushorts
  float* cat   = (float*)(p_bf + 7077888);                   // 1622016
  unsigned short* Bq  = (unsigned short*)(cat + 1622016);    // 294912 ushorts
  unsigned short* Vq  = Bq + 294912;                         // 884736 ushorts
  unsigned short* afT = Vq + 884736;                         // 2048 ushorts
  unsigned short* augT= afT + 2048;                          // 393216 ushorts
  float* Pp    = (float*)(augT + 393216);                    // 7077888 floats
  float* msbuf = Pp + 7077888;                               // 110592 floats
  float* Wall  = msbuf + 110592;                             // 442368 floats
  unsigned short* Wout_bf = (unsigned short*)(Wall + 442368);// 811008 ushorts

  k_prep_w<<<4896, 256, 0, stream>>>(Wq, Wkv, Wqp, Wkvp, Wout, Wall, Wout_bf);
  k_projg<<<96, 384, 0, stream>>>(s, Wall, rot, trans, bq, bkv, bqp, bkvp,
                                  q, kk, vv, qpts, kvpts);
  k_prep_all<<<672, 256, 0, stream>>>(kk, kvpts, Wb, q, qpts, bb, head_w, vv,
                                      Bq, afT, augT, Vq);
  k_zpass<<<dim3(6, 768), 512, 0, stream>>>(z, Bq, afT, augT, p_bf, Pp, msbuf);
  k_comb<<<768, 256, 0, stream>>>(Pp, msbuf, p_bf, cat);
  k_ov<<<dim3(48, 12), 256, 0, stream>>>(p_bf, Vq, rot, trans, cat);
  k_out<<<256, 384, 0, stream>>>(cat, Wout_bf, bout, out);
}